// Round 5
// baseline (645.139 us; speedup 1.0000x reference)
//
#include <hip/hip_runtime.h>

#define N_NODES 100000
#define N_EDGES 1600000
#define IN_DIM 128
#define DIM_H 64
#define N_GRAPHS 64

#define BKT_BITS 9
#define BKT_SIZE 512
#define NBUCKET ((N_NODES + BKT_SIZE - 1) / BKT_SIZE)  /* 196 */
#define NBLK 256
#define EPB ((N_EDGES + NBLK - 1) / NBLK)              /* 6250 */

__device__ __forceinline__ float relu(float v) { return v > 0.f ? v : 0.f; }
#define BN_SCALE 0.99999500003749968f  /* 1/sqrt(1+1e-5) */

// ---------------- CSR build: 3-phase block-private counting sort ----------------
__global__ __launch_bounds__(256) void edge_count(const int* __restrict__ dst,
                                                  int* __restrict__ cnt) {
  __shared__ int hist[NBUCKET];
  int tid = threadIdx.x, blk = blockIdx.x;
  if (tid < NBUCKET) hist[tid] = 0;
  __syncthreads();
  int beg = blk * EPB, end = beg + EPB > N_EDGES ? N_EDGES : beg + EPB;
  for (int i = beg + tid; i < end; i += 256) atomicAdd(&hist[dst[i] >> BKT_BITS], 1);
  __syncthreads();
  if (tid < NBUCKET) cnt[blk * NBUCKET + tid] = hist[tid];
}

__global__ __launch_bounds__(256) void col_scan(int* __restrict__ cnt,
                                                int* __restrict__ tot) {
  __shared__ int sd[NBLK];
  int b = blockIdx.x, tid = threadIdx.x;
  int v = cnt[tid * NBUCKET + b];
  sd[tid] = v;
  __syncthreads();
  for (int off = 1; off < NBLK; off <<= 1) {
    int t = (tid >= off) ? sd[tid - off] : 0;
    __syncthreads();
    sd[tid] += t;
    __syncthreads();
  }
  cnt[tid * NBUCKET + b] = sd[tid] - v;
  if (tid == NBLK - 1) tot[b] = sd[tid];
}

__global__ void base_scan(const int* __restrict__ tot, int* __restrict__ base) {
  __shared__ int sd[256];
  int tid = threadIdx.x;
  int v = (tid < NBUCKET) ? tot[tid] : 0;
  sd[tid] = v;
  __syncthreads();
  for (int off = 1; off < 256; off <<= 1) {
    int t = (tid >= off) ? sd[tid - off] : 0;
    __syncthreads();
    sd[tid] += t;
    __syncthreads();
  }
  if (tid < NBUCKET) base[tid] = sd[tid] - v;
}

__global__ __launch_bounds__(256) void edge_place(const int* __restrict__ src,
                                                  const int* __restrict__ dst,
                                                  const int* __restrict__ cnt,
                                                  const int* __restrict__ base,
                                                  int* __restrict__ bktbuf) {
  __shared__ int curs[NBUCKET];
  int tid = threadIdx.x, blk = blockIdx.x;
  if (tid < NBUCKET) curs[tid] = base[tid] + cnt[blk * NBUCKET + tid];
  __syncthreads();
  int beg = blk * EPB, end = beg + EPB > N_EDGES ? N_EDGES : beg + EPB;
  for (int i = beg + tid; i < end; i += 256) {
    int d = dst[i];
    int b = d >> BKT_BITS;
    int pos = atomicAdd(&curs[b], 1);
    bktbuf[pos] = src[i] | ((d & (BKT_SIZE - 1)) << 17);
  }
}

__global__ __launch_bounds__(256) void bucket_sort(const int* __restrict__ tot,
                                                   const int* __restrict__ bktbase,
                                                   const int* __restrict__ bktbuf,
                                                   int* __restrict__ rp,
                                                   int* __restrict__ ci) {
  __shared__ int hist[BKT_SIZE];
  __shared__ int partial[256];
  int b = blockIdx.x;
  int tid = threadIdx.x;
  int nb = tot[b];
  int base = bktbase[b];
  const int* buf = bktbuf + base;
  hist[tid] = 0;
  hist[tid + 256] = 0;
  __syncthreads();
  for (int i = tid; i < nb; i += 256) atomicAdd(&hist[buf[i] >> 17], 1);
  __syncthreads();
  int v0 = hist[2 * tid], v1 = hist[2 * tid + 1];
  int s = v0 + v1;
  partial[tid] = s;
  __syncthreads();
  for (int off = 1; off < 256; off <<= 1) {
    int t = (tid >= off) ? partial[tid - off] : 0;
    __syncthreads();
    partial[tid] += t;
    __syncthreads();
  }
  int excl = partial[tid] - s;
  int node0 = b * BKT_SIZE + 2 * tid;
  if (node0 < N_NODES) rp[node0] = base + excl;
  if (node0 + 1 < N_NODES) rp[node0 + 1] = base + excl + v0;
  __syncthreads();
  hist[2 * tid] = excl;
  hist[2 * tid + 1] = excl + v0;
  __syncthreads();
  for (int i = tid; i < nb; i += 256) {
    int p = buf[i];
    int pos = atomicAdd(&hist[p >> 17], 1);
    ci[base + pos] = p & 0x1FFFF;
  }
  if (b == 0 && tid == 0) rp[N_NODES] = N_EDGES;
}

// ---------------- aggregation: float4 gathers, 4 edges per wave-instr ----------------
__global__ __launch_bounds__(256) void agg_kernel(const float* __restrict__ hin,
                                                  const int* __restrict__ rp,
                                                  const int* __restrict__ ci,
                                                  float* __restrict__ out) {
  int wid = (blockIdx.x * 256 + threadIdx.x) >> 6;
  if (wid >= N_NODES) return;
  int lane = threadIdx.x & 63;
  int eg = lane >> 4;        // edge subgroup 0..3
  int dq = lane & 15;        // float4 slot within row
  int beg = rp[wid], end = rp[wid + 1];
  float4 a0 = {0.f, 0.f, 0.f, 0.f}, a1 = {0.f, 0.f, 0.f, 0.f};
  int e = beg;
  for (; e + 8 <= end; e += 8) {
    int i0 = ci[e + eg];
    int i1 = ci[e + 4 + eg];
    float4 v0 = *(const float4*)(hin + (size_t)i0 * 64 + dq * 4);
    float4 v1 = *(const float4*)(hin + (size_t)i1 * 64 + dq * 4);
    a0.x += v0.x; a0.y += v0.y; a0.z += v0.z; a0.w += v0.w;
    a1.x += v1.x; a1.y += v1.y; a1.z += v1.z; a1.w += v1.w;
  }
  for (; e < end; e += 4) {
    if (e + eg < end) {
      int i0 = ci[e + eg];
      float4 v0 = *(const float4*)(hin + (size_t)i0 * 64 + dq * 4);
      a0.x += v0.x; a0.y += v0.y; a0.z += v0.z; a0.w += v0.w;
    }
  }
  a0.x += a1.x; a0.y += a1.y; a0.z += a1.z; a0.w += a1.w;
  a0.x += __shfl_xor(a0.x, 16, 64); a0.y += __shfl_xor(a0.y, 16, 64);
  a0.z += __shfl_xor(a0.z, 16, 64); a0.w += __shfl_xor(a0.w, 16, 64);
  a0.x += __shfl_xor(a0.x, 32, 64); a0.y += __shfl_xor(a0.y, 32, 64);
  a0.z += __shfl_xor(a0.z, 32, 64); a0.w += __shfl_xor(a0.w, 32, 64);
  if (eg == 0) {
    float4 self = *(const float4*)(hin + (size_t)wid * 64 + dq * 4);
    float4 r;
    r.x = a0.x + self.x; r.y = a0.y + self.y;
    r.z = a0.z + self.z; r.w = a0.w + self.w;
    *(float4*)(out + (size_t)wid * 64 + dq * 4) = r;
  }
}

// ---------------- tiled fp32 GEMM building blocks ----------------
// lx: [128 nodes][65]; lw: wT [64 outs][65]; thread tile 8 nodes x 8 outs.
__device__ __forceinline__ void gemm8x8(const float* __restrict__ lx,
                                        const float* __restrict__ lw,
                                        float acc[8][8], int tn, int to) {
  const float* xa = lx + tn * 8 * 65;
  const float* wb = lw + to * 8 * 65;
  for (int k0 = 0; k0 < 64; k0 += 4) {
    float4 a[8], b[8];
#pragma unroll
    for (int i = 0; i < 8; ++i) a[i] = *(const float4*)(xa + i * 65 + k0);
#pragma unroll
    for (int j = 0; j < 8; ++j) b[j] = *(const float4*)(wb + j * 65 + k0);
#pragma unroll
    for (int i = 0; i < 8; ++i)
#pragma unroll
      for (int j = 0; j < 8; ++j) {
        acc[i][j] = fmaf(a[i].x, b[j].x, acc[i][j]);
        acc[i][j] = fmaf(a[i].y, b[j].y, acc[i][j]);
        acc[i][j] = fmaf(a[i].z, b[j].z, acc[i][j]);
        acc[i][j] = fmaf(a[i].w, b[j].w, acc[i][j]);
      }
  }
}

__device__ __forceinline__ void stage_x(const float* __restrict__ gx, int nbase,
                                        int RL, int ko, float* lx, int tid) {
#pragma unroll
  for (int it = 0; it < 16; ++it) {
    int idx = tid + it * 128;
    int node = idx >> 4, kq = idx & 15;
    float4 v = {0.f, 0.f, 0.f, 0.f};
    if (nbase + node < N_NODES)
      v = *(const float4*)(gx + (size_t)(nbase + node) * RL + ko + kq * 4);
    *(float4*)(lx + node * 65 + kq * 4) = v;
  }
}

// gw: [K][64] row-major -> lw: wT [out][65]
__device__ __forceinline__ void stage_w(const float* __restrict__ gw, int ko,
                                        float* lw, int tid) {
#pragma unroll
  for (int it = 0; it < 8; ++it) {
    int idx = tid + it * 128;
    int k = idx >> 4, oq = idx & 15;
    float4 v = *(const float4*)(gw + (size_t)(ko + k) * 64 + oq * 4);
    lw[(oq * 4 + 0) * 65 + k] = v.x;
    lw[(oq * 4 + 1) * 65 + k] = v.y;
    lw[(oq * 4 + 2) * 65 + k] = v.z;
    lw[(oq * 4 + 3) * 65 + k] = v.w;
  }
}

// ---------------- proj: x[100000][128] @ W0a[128][64], no bias ----------------
__global__ __launch_bounds__(128) void proj_kernel(const float* __restrict__ x,
                                                   const float* __restrict__ W0a,
                                                   float* __restrict__ out) {
  __shared__ float lx[128 * 65];
  __shared__ float lw[64 * 65];
  int tid = threadIdx.x;
  int nbase = blockIdx.x * 128;
  int tn = tid >> 3, to = tid & 7;
  float acc[8][8];
#pragma unroll
  for (int i = 0; i < 8; ++i)
#pragma unroll
    for (int j = 0; j < 8; ++j) acc[i][j] = 0.f;
#pragma unroll
  for (int ph = 0; ph < 2; ++ph) {
    if (ph) __syncthreads();
    stage_x(x, nbase, 128, ph * 64, lx, tid);
    stage_w(W0a, ph * 64, lw, tid);
    __syncthreads();
    gemm8x8(lx, lw, acc, tn, to);
  }
#pragma unroll
  for (int i = 0; i < 8; ++i) {
    int node = nbase + tn * 8 + i;
    if (node < N_NODES) {
      float4 s0 = {acc[i][0], acc[i][1], acc[i][2], acc[i][3]};
      float4 s1 = {acc[i][4], acc[i][5], acc[i][6], acc[i][7]};
      *(float4*)(out + (size_t)node * 64 + to * 8) = s0;
      *(float4*)(out + (size_t)node * 64 + to * 8 + 4) = s1;
    }
  }
}

// ---------------- conv0 tail: elementwise(z) @ W0b + b0b, relu ----------------
__global__ __launch_bounds__(128) void mlp0_kernel(const float* __restrict__ zin,
                                                   const float* __restrict__ ba,
                                                   const float* __restrict__ g,
                                                   const float* __restrict__ be,
                                                   const float* __restrict__ Wb,
                                                   const float* __restrict__ bb,
                                                   float* __restrict__ out) {
  __shared__ float lx[128 * 65];
  __shared__ float lw[64 * 65];
  int tid = threadIdx.x;
  int nbase = blockIdx.x * 128;
  int tn = tid >> 3, to = tid & 7;
  // columns this thread stages are fixed: (tid&15)*4 .. +3
  int c0 = (tid & 15) * 4;
  float4 bav = *(const float4*)(ba + c0);
  float4 gv4 = *(const float4*)(g + c0);
  float4 bev4 = *(const float4*)(be + c0);
#pragma unroll
  for (int it = 0; it < 16; ++it) {
    int idx = tid + it * 128;
    int node = idx >> 4, kq = idx & 15;
    float4 v = {0.f, 0.f, 0.f, 0.f};
    if (nbase + node < N_NODES)
      v = *(const float4*)(zin + (size_t)(nbase + node) * 64 + kq * 4);
    v.x = relu(fmaf((v.x + bav.x) * BN_SCALE, gv4.x, bev4.x));
    v.y = relu(fmaf((v.y + bav.y) * BN_SCALE, gv4.y, bev4.y));
    v.z = relu(fmaf((v.z + bav.z) * BN_SCALE, gv4.z, bev4.z));
    v.w = relu(fmaf((v.w + bav.w) * BN_SCALE, gv4.w, bev4.w));
    *(float4*)(lx + node * 65 + kq * 4) = v;
  }
  stage_w(Wb, 0, lw, tid);
  __syncthreads();
  float4 bb0 = *(const float4*)(bb + to * 8);
  float4 bb1 = *(const float4*)(bb + to * 8 + 4);
  float acc[8][8];
#pragma unroll
  for (int i = 0; i < 8; ++i) {
    acc[i][0] = bb0.x; acc[i][1] = bb0.y; acc[i][2] = bb0.z; acc[i][3] = bb0.w;
    acc[i][4] = bb1.x; acc[i][5] = bb1.y; acc[i][6] = bb1.z; acc[i][7] = bb1.w;
  }
  gemm8x8(lx, lw, acc, tn, to);
#pragma unroll
  for (int i = 0; i < 8; ++i) {
    int node = nbase + tn * 8 + i;
    if (node < N_NODES) {
      float4 s0 = {relu(acc[i][0]), relu(acc[i][1]), relu(acc[i][2]), relu(acc[i][3])};
      float4 s1 = {relu(acc[i][4]), relu(acc[i][5]), relu(acc[i][6]), relu(acc[i][7])};
      *(float4*)(out + (size_t)node * 64 + to * 8) = s0;
      *(float4*)(out + (size_t)node * 64 + to * 8 + 4) = s1;
    }
  }
}

// ---------------- convs 1,2: z @ Wa+ba, BN, relu, @ Wb+bb, relu ----------------
__global__ __launch_bounds__(128) void mlp2_kernel(const float* __restrict__ zin,
                                                   const float* __restrict__ Wa,
                                                   const float* __restrict__ ba,
                                                   const float* __restrict__ g,
                                                   const float* __restrict__ be,
                                                   const float* __restrict__ Wb,
                                                   const float* __restrict__ bb,
                                                   float* __restrict__ out) {
  __shared__ float lx[128 * 65];
  __shared__ float lw[64 * 65];
  int tid = threadIdx.x;
  int nbase = blockIdx.x * 128;
  int tn = tid >> 3, to = tid & 7;
  stage_x(zin, nbase, 64, 0, lx, tid);
  stage_w(Wa, 0, lw, tid);
  float4 ba0 = *(const float4*)(ba + to * 8);
  float4 ba1 = *(const float4*)(ba + to * 8 + 4);
  float acc[8][8];
#pragma unroll
  for (int i = 0; i < 8; ++i) {
    acc[i][0] = ba0.x; acc[i][1] = ba0.y; acc[i][2] = ba0.z; acc[i][3] = ba0.w;
    acc[i][4] = ba1.x; acc[i][5] = ba1.y; acc[i][6] = ba1.z; acc[i][7] = ba1.w;
  }
  __syncthreads();
  gemm8x8(lx, lw, acc, tn, to);
  float4 g0v = *(const float4*)(g + to * 8);
  float4 g1v = *(const float4*)(g + to * 8 + 4);
  float4 be0v = *(const float4*)(be + to * 8);
  float4 be1v = *(const float4*)(be + to * 8 + 4);
  __syncthreads();  // all gemm reads of lx/lw complete
#pragma unroll
  for (int i = 0; i < 8; ++i) {
    float4 s0, s1;
    s0.x = relu(fmaf(acc[i][0] * BN_SCALE, g0v.x, be0v.x));
    s0.y = relu(fmaf(acc[i][1] * BN_SCALE, g0v.y, be0v.y));
    s0.z = relu(fmaf(acc[i][2] * BN_SCALE, g0v.z, be0v.z));
    s0.w = relu(fmaf(acc[i][3] * BN_SCALE, g0v.w, be0v.w));
    s1.x = relu(fmaf(acc[i][4] * BN_SCALE, g1v.x, be1v.x));
    s1.y = relu(fmaf(acc[i][5] * BN_SCALE, g1v.y, be1v.y));
    s1.z = relu(fmaf(acc[i][6] * BN_SCALE, g1v.z, be1v.z));
    s1.w = relu(fmaf(acc[i][7] * BN_SCALE, g1v.w, be1v.w));
    *(float4*)(lx + (tn * 8 + i) * 65 + to * 8) = s0;
    *(float4*)(lx + (tn * 8 + i) * 65 + to * 8 + 4) = s1;
  }
  stage_w(Wb, 0, lw, tid);
  __syncthreads();
  float4 bb0 = *(const float4*)(bb + to * 8);
  float4 bb1 = *(const float4*)(bb + to * 8 + 4);
#pragma unroll
  for (int i = 0; i < 8; ++i) {
    acc[i][0] = bb0.x; acc[i][1] = bb0.y; acc[i][2] = bb0.z; acc[i][3] = bb0.w;
    acc[i][4] = bb1.x; acc[i][5] = bb1.y; acc[i][6] = bb1.z; acc[i][7] = bb1.w;
  }
  gemm8x8(lx, lw, acc, tn, to);
#pragma unroll
  for (int i = 0; i < 8; ++i) {
    int node = nbase + tn * 8 + i;
    if (node < N_NODES) {
      float4 s0 = {relu(acc[i][0]), relu(acc[i][1]), relu(acc[i][2]), relu(acc[i][3])};
      float4 s1 = {relu(acc[i][4]), relu(acc[i][5]), relu(acc[i][6]), relu(acc[i][7])};
      *(float4*)(out + (size_t)node * 64 + to * 8) = s0;
      *(float4*)(out + (size_t)node * 64 + to * 8 + 4) = s1;
    }
  }
}

// ---------------- pool ----------------
__global__ __launch_bounds__(256) void pool_kernel(const float* __restrict__ h,
                                                   const int* __restrict__ batch,
                                                   float* __restrict__ hp) {
  const int CH = (N_NODES + 1023) / 1024;
  int w = (blockIdx.x * blockDim.x + threadIdx.x) >> 6;
  int lane = threadIdx.x & 63;
  int start = w * CH;
  if (start >= N_NODES) return;
  int end = start + CH;
  if (end > N_NODES) end = N_NODES;
  int cur = batch[start];
  float acc = 0.f;
  for (int n = start; n < end; ++n) {
    int b = batch[n];
    if (b != cur) {
      atomicAdd(&hp[cur * 64 + lane], acc);
      acc = 0.f;
      cur = b;
    }
    acc += h[n * 64 + lane];
  }
  atomicAdd(&hp[cur * 64 + lane], acc);
}

// ---------------- classifier: 64 blocks (graph) x 64 threads (dim) ----------------
__global__ __launch_bounds__(64) void cls_kernel(const float* __restrict__ hp,
                                                 const float* __restrict__ Wl1,
                                                 const float* __restrict__ bl1,
                                                 const float* __restrict__ Wl2,
                                                 const float* __restrict__ bl2,
                                                 float* __restrict__ out) {
  int g = blockIdx.x;
  int d = threadIdx.x;
  const float* hrow = hp + g * 64;
  float acc = bl1[d];
#pragma unroll 8
  for (int k = 0; k < 64; ++k) {
    float v = hrow[k];
    float w = Wl1[k * 64 + d] + Wl1[(64 + k) * 64 + d] + Wl1[(128 + k) * 64 + d];
    acc = fmaf(v, w, acc);
  }
  float t = relu(acc);
  float p0 = t * Wl2[d * 2 + 0];
  float p1 = t * Wl2[d * 2 + 1];
#pragma unroll
  for (int off = 32; off > 0; off >>= 1) {
    p0 += __shfl_xor(p0, off, 64);
    p1 += __shfl_xor(p1, off, 64);
  }
  if (d == 0) {
    float z0 = p0 + bl2[0];
    float z1 = p1 + bl2[1];
    float m = fmaxf(z0, z1);
    float lse = m + logf(expf(z0 - m) + expf(z1 - m));
    out[g * 2 + 0] = z0 - lse;
    out[g * 2 + 1] = z1 - lse;
  }
}

extern "C" void kernel_launch(void* const* d_in, const int* in_sizes, int n_in,
                              void* d_out, int out_size, void* d_ws, size_t ws_size,
                              hipStream_t stream) {
  const float* x   = (const float*)d_in[0];
  const int*   ei  = (const int*)d_in[1];
  const int*   bat = (const int*)d_in[2];
  const float* W0a = (const float*)d_in[3];
  const float* b0a = (const float*)d_in[4];
  const float* g0  = (const float*)d_in[5];
  const float* be0 = (const float*)d_in[6];
  const float* W0b = (const float*)d_in[7];
  const float* b0b = (const float*)d_in[8];
  const float* Wsa = (const float*)d_in[9];
  const float* bsa = (const float*)d_in[10];
  const float* gs  = (const float*)d_in[11];
  const float* bes = (const float*)d_in[12];
  const float* Wsb = (const float*)d_in[13];
  const float* bsb = (const float*)d_in[14];
  const float* Wl1 = (const float*)d_in[15];
  const float* bl1 = (const float*)d_in[16];
  const float* Wl2 = (const float*)d_in[17];
  const float* bl2 = (const float*)d_in[18];
  const int* src = ei;
  const int* dst = ei + N_EDGES;

  char* ws = (char*)d_ws;
  size_t off = 0;
  auto alloc = [&](size_t bytes) { void* p = ws + off; off += (bytes + 255) & ~255ull; return p; };
  int* rp      = (int*)alloc((size_t)(N_NODES + 1) * 4);
  int* cnt     = (int*)alloc((size_t)NBLK * NBUCKET * 4);
  int* tot     = (int*)alloc((size_t)NBUCKET * 4);
  int* bktbase = (int*)alloc((size_t)NBUCKET * 4);
  int* ci      = (int*)alloc((size_t)N_EDGES * 4);
  float* bufA  = (float*)alloc((size_t)N_NODES * 64 * 4);
  float* bufZ  = (float*)alloc((size_t)N_NODES * 64 * 4);
  float* hp    = (float*)alloc((size_t)N_GRAPHS * 64 * 4);
  int* bktbuf  = (int*)bufZ;  // alias: consumed before bufZ first written

  hipMemsetAsync(hp, 0, (size_t)N_GRAPHS * 64 * 4, stream);

  edge_count<<<NBLK, 256, 0, stream>>>(dst, cnt);
  col_scan<<<NBUCKET, NBLK, 0, stream>>>(cnt, tot);
  base_scan<<<1, 256, 0, stream>>>(tot, bktbase);
  edge_place<<<NBLK, 256, 0, stream>>>(src, dst, cnt, bktbase, bktbuf);
  bucket_sort<<<NBUCKET, 256, 0, stream>>>(tot, bktbase, bktbuf, rp, ci);

  const int MB = (N_NODES + 127) / 128;    // 782
  const int AB = (N_NODES + 3) / 4;        // 25000

  proj_kernel<<<MB, 128, 0, stream>>>(x, W0a, bufA);
  agg_kernel<<<AB, 256, 0, stream>>>(bufA, rp, ci, bufZ);
  mlp0_kernel<<<MB, 128, 0, stream>>>(bufZ, b0a, g0, be0, W0b, b0b, bufA);

  for (int l = 0; l < 2; ++l) {
    agg_kernel<<<AB, 256, 0, stream>>>(bufA, rp, ci, bufZ);
    mlp2_kernel<<<MB, 128, 0, stream>>>(bufZ, Wsa + l * 4096, bsa + l * 64, gs + l * 64,
                                        bes + l * 64, Wsb + l * 4096, bsb + l * 64, bufA);
  }

  pool_kernel<<<256, 256, 0, stream>>>(bufA, bat, hp);
  cls_kernel<<<N_GRAPHS, 64, 0, stream>>>(hp, Wl1, bl1, Wl2, bl2, (float*)d_out);
}

// Round 6
// 457.036 us; speedup vs baseline: 1.4116x; 1.4116x over previous
//
#include <hip/hip_runtime.h>

#define N_NODES 100000
#define N_EDGES 1600000
#define IN_DIM 128
#define DIM_H 64
#define N_GRAPHS 64

#define BKT_BITS 9
#define BKT_SIZE 512
#define NBUCKET ((N_NODES + BKT_SIZE - 1) / BKT_SIZE)  /* 196 */
#define NBLK 256
#define EPB ((N_EDGES + NBLK - 1) / NBLK)              /* 6250 */

__device__ __forceinline__ float relu(float v) { return v > 0.f ? v : 0.f; }
#define BN_SCALE 0.99999500003749968f  /* 1/sqrt(1+1e-5) */

// ---------------- CSR build: 3-phase block-private counting sort ----------------
__global__ __launch_bounds__(256) void edge_count(const int* __restrict__ dst,
                                                  int* __restrict__ cnt) {
  __shared__ int hist[NBUCKET];
  int tid = threadIdx.x, blk = blockIdx.x;
  if (tid < NBUCKET) hist[tid] = 0;
  __syncthreads();
  int beg = blk * EPB, end = beg + EPB > N_EDGES ? N_EDGES : beg + EPB;
  for (int i = beg + tid; i < end; i += 256) atomicAdd(&hist[dst[i] >> BKT_BITS], 1);
  __syncthreads();
  if (tid < NBUCKET) cnt[blk * NBUCKET + tid] = hist[tid];
}

__global__ __launch_bounds__(256) void col_scan(int* __restrict__ cnt,
                                                int* __restrict__ tot) {
  __shared__ int sd[NBLK];
  int b = blockIdx.x, tid = threadIdx.x;
  int v = cnt[tid * NBUCKET + b];
  sd[tid] = v;
  __syncthreads();
  for (int off = 1; off < NBLK; off <<= 1) {
    int t = (tid >= off) ? sd[tid - off] : 0;
    __syncthreads();
    sd[tid] += t;
    __syncthreads();
  }
  cnt[tid * NBUCKET + b] = sd[tid] - v;
  if (tid == NBLK - 1) tot[b] = sd[tid];
}

__global__ void base_scan(const int* __restrict__ tot, int* __restrict__ base) {
  __shared__ int sd[256];
  int tid = threadIdx.x;
  int v = (tid < NBUCKET) ? tot[tid] : 0;
  sd[tid] = v;
  __syncthreads();
  for (int off = 1; off < 256; off <<= 1) {
    int t = (tid >= off) ? sd[tid - off] : 0;
    __syncthreads();
    sd[tid] += t;
    __syncthreads();
  }
  if (tid < NBUCKET) base[tid] = sd[tid] - v;
}

__global__ __launch_bounds__(256) void edge_place(const int* __restrict__ src,
                                                  const int* __restrict__ dst,
                                                  const int* __restrict__ cnt,
                                                  const int* __restrict__ base,
                                                  int* __restrict__ bktbuf) {
  __shared__ int curs[NBUCKET];
  int tid = threadIdx.x, blk = blockIdx.x;
  if (tid < NBUCKET) curs[tid] = base[tid] + cnt[blk * NBUCKET + tid];
  __syncthreads();
  int beg = blk * EPB, end = beg + EPB > N_EDGES ? N_EDGES : beg + EPB;
  for (int i = beg + tid; i < end; i += 256) {
    int d = dst[i];
    int b = d >> BKT_BITS;
    int pos = atomicAdd(&curs[b], 1);
    bktbuf[pos] = src[i] | ((d & (BKT_SIZE - 1)) << 17);
  }
}

__global__ __launch_bounds__(256) void bucket_sort(const int* __restrict__ tot,
                                                   const int* __restrict__ bktbase,
                                                   const int* __restrict__ bktbuf,
                                                   int* __restrict__ rp,
                                                   int* __restrict__ ci) {
  __shared__ int hist[BKT_SIZE];
  __shared__ int partial[256];
  int b = blockIdx.x;
  int tid = threadIdx.x;
  int nb = tot[b];
  int base = bktbase[b];
  const int* buf = bktbuf + base;
  hist[tid] = 0;
  hist[tid + 256] = 0;
  __syncthreads();
  for (int i = tid; i < nb; i += 256) atomicAdd(&hist[buf[i] >> 17], 1);
  __syncthreads();
  int v0 = hist[2 * tid], v1 = hist[2 * tid + 1];
  int s = v0 + v1;
  partial[tid] = s;
  __syncthreads();
  for (int off = 1; off < 256; off <<= 1) {
    int t = (tid >= off) ? partial[tid - off] : 0;
    __syncthreads();
    partial[tid] += t;
    __syncthreads();
  }
  int excl = partial[tid] - s;
  int node0 = b * BKT_SIZE + 2 * tid;
  if (node0 < N_NODES) rp[node0] = base + excl;
  if (node0 + 1 < N_NODES) rp[node0 + 1] = base + excl + v0;
  __syncthreads();
  hist[2 * tid] = excl;
  hist[2 * tid + 1] = excl + v0;
  __syncthreads();
  for (int i = tid; i < nb; i += 256) {
    int p = buf[i];
    int pos = atomicAdd(&hist[p >> 17], 1);
    ci[base + pos] = p & 0x1FFFF;
  }
  if (b == 0 && tid == 0) rp[N_NODES] = N_EDGES;
}

// ---------------- aggregation: float4 gathers, 4 edges per wave-instr ----------------
__global__ __launch_bounds__(256) void agg_kernel(const float* __restrict__ hin,
                                                  const int* __restrict__ rp,
                                                  const int* __restrict__ ci,
                                                  float* __restrict__ out) {
  int wid = (blockIdx.x * 256 + threadIdx.x) >> 6;
  if (wid >= N_NODES) return;
  int lane = threadIdx.x & 63;
  int eg = lane >> 4;
  int dq = lane & 15;
  int beg = rp[wid], end = rp[wid + 1];
  float4 a0 = {0.f, 0.f, 0.f, 0.f}, a1 = {0.f, 0.f, 0.f, 0.f};
  int e = beg;
  for (; e + 8 <= end; e += 8) {
    int i0 = ci[e + eg];
    int i1 = ci[e + 4 + eg];
    float4 v0 = *(const float4*)(hin + (size_t)i0 * 64 + dq * 4);
    float4 v1 = *(const float4*)(hin + (size_t)i1 * 64 + dq * 4);
    a0.x += v0.x; a0.y += v0.y; a0.z += v0.z; a0.w += v0.w;
    a1.x += v1.x; a1.y += v1.y; a1.z += v1.z; a1.w += v1.w;
  }
  for (; e < end; e += 4) {
    if (e + eg < end) {
      int i0 = ci[e + eg];
      float4 v0 = *(const float4*)(hin + (size_t)i0 * 64 + dq * 4);
      a0.x += v0.x; a0.y += v0.y; a0.z += v0.z; a0.w += v0.w;
    }
  }
  a0.x += a1.x; a0.y += a1.y; a0.z += a1.z; a0.w += a1.w;
  a0.x += __shfl_xor(a0.x, 16, 64); a0.y += __shfl_xor(a0.y, 16, 64);
  a0.z += __shfl_xor(a0.z, 16, 64); a0.w += __shfl_xor(a0.w, 16, 64);
  a0.x += __shfl_xor(a0.x, 32, 64); a0.y += __shfl_xor(a0.y, 32, 64);
  a0.z += __shfl_xor(a0.z, 32, 64); a0.w += __shfl_xor(a0.w, 32, 64);
  if (eg == 0) {
    float4 self = *(const float4*)(hin + (size_t)wid * 64 + dq * 4);
    float4 r;
    r.x = a0.x + self.x; r.y = a0.y + self.y;
    r.z = a0.z + self.z; r.w = a0.w + self.w;
    *(float4*)(out + (size_t)wid * 64 + dq * 4) = r;
  }
}

// ---------------- row-local GEMM: thread-per-node, W broadcast from LDS ----------------
// K: inner dim. PRE: 0 none, 1 t=relu((x+pba)*C*pg+pbe) on input.
// EPI: 0 none (no bias), 1 relu(acc+bias), 2 relu((acc+bias)*C*g+be).
template <int K, int PRE, int EPI>
__global__ __launch_bounds__(128) void gemm_kernel(const float* __restrict__ in,
                                                   const float* __restrict__ W,
                                                   const float* __restrict__ pba,
                                                   const float* __restrict__ pg,
                                                   const float* __restrict__ pbe,
                                                   const float* __restrict__ bias,
                                                   const float* __restrict__ g,
                                                   const float* __restrict__ be,
                                                   float* __restrict__ out) {
  __shared__ float lw[K * 64];
  int tid = threadIdx.x;
#pragma unroll
  for (int it = 0; it < K * 64 / 512; ++it) {
    int idx = (tid + it * 128) * 4;
    *(float4*)(lw + idx) = *(const float4*)(W + idx);
  }
  __syncthreads();
  int node = blockIdx.x * 128 + tid;
  bool valid = node < N_NODES;
  int nclamp = valid ? node : N_NODES - 1;
  const float* xrow = in + (size_t)nclamp * K;
  float acc[64];
  if (EPI == 0) {
#pragma unroll
    for (int d = 0; d < 64; ++d) acc[d] = 0.f;
  } else {
#pragma unroll
    for (int d4 = 0; d4 < 16; ++d4) {
      float4 b4 = *(const float4*)(bias + d4 * 4);
      acc[d4 * 4 + 0] = b4.x; acc[d4 * 4 + 1] = b4.y;
      acc[d4 * 4 + 2] = b4.z; acc[d4 * 4 + 3] = b4.w;
    }
  }
  for (int c = 0; c < K / 16; ++c) {
    float xb[16];
#pragma unroll
    for (int q = 0; q < 4; ++q) {
      float4 v = *(const float4*)(xrow + c * 16 + q * 4);
      xb[q * 4 + 0] = v.x; xb[q * 4 + 1] = v.y;
      xb[q * 4 + 2] = v.z; xb[q * 4 + 3] = v.w;
    }
    if (PRE == 1) {
#pragma unroll
      for (int q = 0; q < 4; ++q) {
        float4 bav = *(const float4*)(pba + c * 16 + q * 4);
        float4 gv = *(const float4*)(pg + c * 16 + q * 4);
        float4 bev = *(const float4*)(pbe + c * 16 + q * 4);
        xb[q * 4 + 0] = relu(fmaf((xb[q * 4 + 0] + bav.x) * BN_SCALE, gv.x, bev.x));
        xb[q * 4 + 1] = relu(fmaf((xb[q * 4 + 1] + bav.y) * BN_SCALE, gv.y, bev.y));
        xb[q * 4 + 2] = relu(fmaf((xb[q * 4 + 2] + bav.z) * BN_SCALE, gv.z, bev.z));
        xb[q * 4 + 3] = relu(fmaf((xb[q * 4 + 3] + bav.w) * BN_SCALE, gv.w, bev.w));
      }
    }
    const float* wc = lw + c * 16 * 64;
#pragma unroll
    for (int kk = 0; kk < 16; ++kk) {
      float xk = xb[kk];
#pragma unroll
      for (int d4 = 0; d4 < 16; ++d4) {
        float4 w4 = *(const float4*)(wc + kk * 64 + d4 * 4);
        acc[d4 * 4 + 0] = fmaf(xk, w4.x, acc[d4 * 4 + 0]);
        acc[d4 * 4 + 1] = fmaf(xk, w4.y, acc[d4 * 4 + 1]);
        acc[d4 * 4 + 2] = fmaf(xk, w4.z, acc[d4 * 4 + 2]);
        acc[d4 * 4 + 3] = fmaf(xk, w4.w, acc[d4 * 4 + 3]);
      }
    }
  }
  if (valid) {
    float* orow = out + (size_t)node * 64;
#pragma unroll
    for (int d4 = 0; d4 < 16; ++d4) {
      float4 r = {acc[d4 * 4 + 0], acc[d4 * 4 + 1], acc[d4 * 4 + 2], acc[d4 * 4 + 3]};
      if (EPI == 1) {
        r.x = relu(r.x); r.y = relu(r.y); r.z = relu(r.z); r.w = relu(r.w);
      } else if (EPI == 2) {
        float4 g4 = *(const float4*)(g + d4 * 4);
        float4 be4 = *(const float4*)(be + d4 * 4);
        r.x = relu(fmaf(r.x * BN_SCALE, g4.x, be4.x));
        r.y = relu(fmaf(r.y * BN_SCALE, g4.y, be4.y));
        r.z = relu(fmaf(r.z * BN_SCALE, g4.z, be4.z));
        r.w = relu(fmaf(r.w * BN_SCALE, g4.w, be4.w));
      }
      *(float4*)(orow + d4 * 4) = r;
    }
  }
}

// ---------------- pool ----------------
__global__ __launch_bounds__(256) void pool_kernel(const float* __restrict__ h,
                                                   const int* __restrict__ batch,
                                                   float* __restrict__ hp) {
  const int CH = (N_NODES + 1023) / 1024;
  int w = (blockIdx.x * blockDim.x + threadIdx.x) >> 6;
  int lane = threadIdx.x & 63;
  int start = w * CH;
  if (start >= N_NODES) return;
  int end = start + CH;
  if (end > N_NODES) end = N_NODES;
  int cur = batch[start];
  float acc = 0.f;
  for (int n = start; n < end; ++n) {
    int b = batch[n];
    if (b != cur) {
      atomicAdd(&hp[cur * 64 + lane], acc);
      acc = 0.f;
      cur = b;
    }
    acc += h[n * 64 + lane];
  }
  atomicAdd(&hp[cur * 64 + lane], acc);
}

// ---------------- classifier ----------------
__global__ __launch_bounds__(64) void cls_kernel(const float* __restrict__ hp,
                                                 const float* __restrict__ Wl1,
                                                 const float* __restrict__ bl1,
                                                 const float* __restrict__ Wl2,
                                                 const float* __restrict__ bl2,
                                                 float* __restrict__ out) {
  int g = blockIdx.x;
  int d = threadIdx.x;
  const float* hrow = hp + g * 64;
  float acc = bl1[d];
#pragma unroll 8
  for (int k = 0; k < 64; ++k) {
    float v = hrow[k];
    float w = Wl1[k * 64 + d] + Wl1[(64 + k) * 64 + d] + Wl1[(128 + k) * 64 + d];
    acc = fmaf(v, w, acc);
  }
  float t = relu(acc);
  float p0 = t * Wl2[d * 2 + 0];
  float p1 = t * Wl2[d * 2 + 1];
#pragma unroll
  for (int off = 32; off > 0; off >>= 1) {
    p0 += __shfl_xor(p0, off, 64);
    p1 += __shfl_xor(p1, off, 64);
  }
  if (d == 0) {
    float z0 = p0 + bl2[0];
    float z1 = p1 + bl2[1];
    float m = fmaxf(z0, z1);
    float lse = m + logf(expf(z0 - m) + expf(z1 - m));
    out[g * 2 + 0] = z0 - lse;
    out[g * 2 + 1] = z1 - lse;
  }
}

extern "C" void kernel_launch(void* const* d_in, const int* in_sizes, int n_in,
                              void* d_out, int out_size, void* d_ws, size_t ws_size,
                              hipStream_t stream) {
  const float* x   = (const float*)d_in[0];
  const int*   ei  = (const int*)d_in[1];
  const int*   bat = (const int*)d_in[2];
  const float* W0a = (const float*)d_in[3];
  const float* b0a = (const float*)d_in[4];
  const float* g0  = (const float*)d_in[5];
  const float* be0 = (const float*)d_in[6];
  const float* W0b = (const float*)d_in[7];
  const float* b0b = (const float*)d_in[8];
  const float* Wsa = (const float*)d_in[9];
  const float* bsa = (const float*)d_in[10];
  const float* gs  = (const float*)d_in[11];
  const float* bes = (const float*)d_in[12];
  const float* Wsb = (const float*)d_in[13];
  const float* bsb = (const float*)d_in[14];
  const float* Wl1 = (const float*)d_in[15];
  const float* bl1 = (const float*)d_in[16];
  const float* Wl2 = (const float*)d_in[17];
  const float* bl2 = (const float*)d_in[18];
  const int* src = ei;
  const int* dst = ei + N_EDGES;

  char* ws = (char*)d_ws;
  size_t off = 0;
  auto alloc = [&](size_t bytes) { void* p = ws + off; off += (bytes + 255) & ~255ull; return p; };
  int* rp      = (int*)alloc((size_t)(N_NODES + 1) * 4);
  int* cnt     = (int*)alloc((size_t)NBLK * NBUCKET * 4);
  int* tot     = (int*)alloc((size_t)NBUCKET * 4);
  int* bktbase = (int*)alloc((size_t)NBUCKET * 4);
  int* ci      = (int*)alloc((size_t)N_EDGES * 4);
  float* bufA  = (float*)alloc((size_t)N_NODES * 64 * 4);
  float* bufZ  = (float*)alloc((size_t)N_NODES * 64 * 4);
  float* hp    = (float*)alloc((size_t)N_GRAPHS * 64 * 4);
  int* bktbuf  = (int*)bufZ;  // alias: consumed before bufZ first written

  hipMemsetAsync(hp, 0, (size_t)N_GRAPHS * 64 * 4, stream);

  edge_count<<<NBLK, 256, 0, stream>>>(dst, cnt);
  col_scan<<<NBUCKET, NBLK, 0, stream>>>(cnt, tot);
  base_scan<<<1, 256, 0, stream>>>(tot, bktbase);
  edge_place<<<NBLK, 256, 0, stream>>>(src, dst, cnt, bktbase, bktbuf);
  bucket_sort<<<NBUCKET, 256, 0, stream>>>(tot, bktbase, bktbuf, rp, ci);

  const int GB = (N_NODES + 127) / 128;    // 782
  const int AB = (N_NODES + 3) / 4;        // 25000

  // conv0: proj (K=128, no epi), agg, then W0b-GEMM with fused pre-BN-relu
  gemm_kernel<128, 0, 0><<<GB, 128, 0, stream>>>(
      x, W0a, nullptr, nullptr, nullptr, nullptr, nullptr, nullptr, bufA);
  agg_kernel<<<AB, 256, 0, stream>>>(bufA, rp, ci, bufZ);
  gemm_kernel<64, 1, 1><<<GB, 128, 0, stream>>>(
      bufZ, W0b, b0a, g0, be0, b0b, nullptr, nullptr, bufA);

  for (int l = 0; l < 2; ++l) {
    agg_kernel<<<AB, 256, 0, stream>>>(bufA, rp, ci, bufZ);
    gemm_kernel<64, 0, 2><<<GB, 128, 0, stream>>>(
        bufZ, Wsa + l * 4096, nullptr, nullptr, nullptr,
        bsa + l * 64, gs + l * 64, bes + l * 64, bufZ);  // in-place (row-local)
    gemm_kernel<64, 0, 1><<<GB, 128, 0, stream>>>(
        bufZ, Wsb + l * 4096, nullptr, nullptr, nullptr,
        bsb + l * 64, nullptr, nullptr, bufA);
  }

  pool_kernel<<<256, 256, 0, stream>>>(bufA, bat, hp);
  cls_kernel<<<N_GRAPHS, 64, 0, stream>>>(hp, Wl1, bl1, Wl2, bl2, (float*)d_out);
}

// Round 7
// 442.663 us; speedup vs baseline: 1.4574x; 1.0325x over previous
//
#include <hip/hip_runtime.h>

#define N_NODES 100000
#define N_EDGES 1600000
#define IN_DIM 128
#define DIM_H 64
#define N_GRAPHS 64

#define BKT_BITS 9
#define BKT_SIZE 512
#define NBUCKET ((N_NODES + BKT_SIZE - 1) / BKT_SIZE)  /* 196 */
#define NBLK 256
#define EPB ((N_EDGES + NBLK - 1) / NBLK)              /* 6250 */

__device__ __forceinline__ float relu(float v) { return v > 0.f ? v : 0.f; }
#define BN_SCALE 0.99999500003749968f  /* 1/sqrt(1+1e-5) */

__device__ __forceinline__ float bf2f(unsigned short u) {
  return __uint_as_float(((unsigned int)u) << 16);
}
__device__ __forceinline__ unsigned short f2bf(float f) {
  unsigned int u = __float_as_uint(f);
  u += 0x7FFFu + ((u >> 16) & 1u);   // round-to-nearest-even
  return (unsigned short)(u >> 16);
}

// ---------------- CSR build: 3-phase block-private counting sort ----------------
__global__ __launch_bounds__(256) void edge_count(const int* __restrict__ dst,
                                                  int* __restrict__ cnt) {
  __shared__ int hist[NBUCKET];
  int tid = threadIdx.x, blk = blockIdx.x;
  if (tid < NBUCKET) hist[tid] = 0;
  __syncthreads();
  int beg = blk * EPB, end = beg + EPB > N_EDGES ? N_EDGES : beg + EPB;
  for (int i = beg + tid; i < end; i += 256) atomicAdd(&hist[dst[i] >> BKT_BITS], 1);
  __syncthreads();
  if (tid < NBUCKET) cnt[blk * NBUCKET + tid] = hist[tid];
}

__global__ __launch_bounds__(256) void col_scan(int* __restrict__ cnt,
                                                int* __restrict__ tot) {
  __shared__ int sd[NBLK];
  int b = blockIdx.x, tid = threadIdx.x;
  int v = cnt[tid * NBUCKET + b];
  sd[tid] = v;
  __syncthreads();
  for (int off = 1; off < NBLK; off <<= 1) {
    int t = (tid >= off) ? sd[tid - off] : 0;
    __syncthreads();
    sd[tid] += t;
    __syncthreads();
  }
  cnt[tid * NBUCKET + b] = sd[tid] - v;
  if (tid == NBLK - 1) tot[b] = sd[tid];
}

__global__ void base_scan(const int* __restrict__ tot, int* __restrict__ base) {
  __shared__ int sd[256];
  int tid = threadIdx.x;
  int v = (tid < NBUCKET) ? tot[tid] : 0;
  sd[tid] = v;
  __syncthreads();
  for (int off = 1; off < 256; off <<= 1) {
    int t = (tid >= off) ? sd[tid - off] : 0;
    __syncthreads();
    sd[tid] += t;
    __syncthreads();
  }
  if (tid < NBUCKET) base[tid] = sd[tid] - v;
}

__global__ __launch_bounds__(256) void edge_place(const int* __restrict__ src,
                                                  const int* __restrict__ dst,
                                                  const int* __restrict__ cnt,
                                                  const int* __restrict__ base,
                                                  int* __restrict__ bktbuf) {
  __shared__ int curs[NBUCKET];
  int tid = threadIdx.x, blk = blockIdx.x;
  if (tid < NBUCKET) curs[tid] = base[tid] + cnt[blk * NBUCKET + tid];
  __syncthreads();
  int beg = blk * EPB, end = beg + EPB > N_EDGES ? N_EDGES : beg + EPB;
  for (int i = beg + tid; i < end; i += 256) {
    int d = dst[i];
    int b = d >> BKT_BITS;
    int pos = atomicAdd(&curs[b], 1);
    bktbuf[pos] = src[i] | ((d & (BKT_SIZE - 1)) << 17);
  }
}

__global__ __launch_bounds__(256) void bucket_sort(const int* __restrict__ tot,
                                                   const int* __restrict__ bktbase,
                                                   const int* __restrict__ bktbuf,
                                                   int* __restrict__ rp,
                                                   int* __restrict__ ci) {
  __shared__ int hist[BKT_SIZE];
  __shared__ int partial[256];
  int b = blockIdx.x;
  int tid = threadIdx.x;
  int nb = tot[b];
  int base = bktbase[b];
  const int* buf = bktbuf + base;
  hist[tid] = 0;
  hist[tid + 256] = 0;
  __syncthreads();
  for (int i = tid; i < nb; i += 256) atomicAdd(&hist[buf[i] >> 17], 1);
  __syncthreads();
  int v0 = hist[2 * tid], v1 = hist[2 * tid + 1];
  int s = v0 + v1;
  partial[tid] = s;
  __syncthreads();
  for (int off = 1; off < 256; off <<= 1) {
    int t = (tid >= off) ? partial[tid - off] : 0;
    __syncthreads();
    partial[tid] += t;
    __syncthreads();
  }
  int excl = partial[tid] - s;
  int node0 = b * BKT_SIZE + 2 * tid;
  if (node0 < N_NODES) rp[node0] = base + excl;
  if (node0 + 1 < N_NODES) rp[node0 + 1] = base + excl + v0;
  __syncthreads();
  hist[2 * tid] = excl;
  hist[2 * tid + 1] = excl + v0;
  __syncthreads();
  for (int i = tid; i < nb; i += 256) {
    int p = buf[i];
    int pos = atomicAdd(&hist[p >> 17], 1);
    ci[base + pos] = p & 0x1FFFF;
  }
  if (b == 0 && tid == 0) rp[N_NODES] = N_EDGES;
}

// ---------------- aggregation: bf16 gathers (128 B rows), fp32 accumulate ----------------
__global__ __launch_bounds__(256) void agg_kernel(const unsigned short* __restrict__ hb,
                                                  const int* __restrict__ rp,
                                                  const int* __restrict__ ci,
                                                  float* __restrict__ out) {
  int wid = (blockIdx.x * 256 + threadIdx.x) >> 6;
  if (wid >= N_NODES) return;
  int lane = threadIdx.x & 63;
  int eg = lane >> 4;        // edge subgroup 0..3
  int dq = lane & 15;        // 4-dim slot within row
  int beg = rp[wid], end = rp[wid + 1];
  float a0 = 0.f, a1 = 0.f, a2 = 0.f, a3 = 0.f;
  float b0 = 0.f, b1 = 0.f, b2 = 0.f, b3 = 0.f;
  int e = beg;
  for (; e + 8 <= end; e += 8) {
    int i0 = ci[e + eg];
    int i1 = ci[e + 4 + eg];
    ushort4 v0 = *(const ushort4*)(hb + (size_t)i0 * 64 + dq * 4);
    ushort4 v1 = *(const ushort4*)(hb + (size_t)i1 * 64 + dq * 4);
    a0 += bf2f(v0.x); a1 += bf2f(v0.y); a2 += bf2f(v0.z); a3 += bf2f(v0.w);
    b0 += bf2f(v1.x); b1 += bf2f(v1.y); b2 += bf2f(v1.z); b3 += bf2f(v1.w);
  }
  for (; e < end; e += 4) {
    if (e + eg < end) {
      ushort4 v0 = *(const ushort4*)(hb + (size_t)ci[e + eg] * 64 + dq * 4);
      a0 += bf2f(v0.x); a1 += bf2f(v0.y); a2 += bf2f(v0.z); a3 += bf2f(v0.w);
    }
  }
  a0 += b0; a1 += b1; a2 += b2; a3 += b3;
  a0 += __shfl_xor(a0, 16, 64); a1 += __shfl_xor(a1, 16, 64);
  a2 += __shfl_xor(a2, 16, 64); a3 += __shfl_xor(a3, 16, 64);
  a0 += __shfl_xor(a0, 32, 64); a1 += __shfl_xor(a1, 32, 64);
  a2 += __shfl_xor(a2, 32, 64); a3 += __shfl_xor(a3, 32, 64);
  if (eg == 0) {
    ushort4 s = *(const ushort4*)(hb + (size_t)wid * 64 + dq * 4);
    float4 r = {a0 + bf2f(s.x), a1 + bf2f(s.y), a2 + bf2f(s.z), a3 + bf2f(s.w)};
    *(float4*)(out + (size_t)wid * 64 + dq * 4) = r;
  }
}

// ---------------- row-local GEMM: thread-per-node, W broadcast from LDS ----------------
// K inner dim. PRE: 1 = relu((x+pba)*C*pg+pbe) on input. EPI: 0 none, 1 relu(+bias),
// 2 relu(((acc+bias))*C*g+be). BF: 1 = write bf16 rows to outb, else fp32 to outf.
template <int K, int PRE, int EPI, int BF>
__global__ __launch_bounds__(128) void gemm_kernel(const float* __restrict__ in,
                                                   const float* __restrict__ W,
                                                   const float* __restrict__ pba,
                                                   const float* __restrict__ pg,
                                                   const float* __restrict__ pbe,
                                                   const float* __restrict__ bias,
                                                   const float* __restrict__ g,
                                                   const float* __restrict__ be,
                                                   float* __restrict__ outf,
                                                   unsigned short* __restrict__ outb) {
  __shared__ float lw[K * 64];
  int tid = threadIdx.x;
#pragma unroll
  for (int it = 0; it < K * 64 / 512; ++it) {
    int idx = (tid + it * 128) * 4;
    *(float4*)(lw + idx) = *(const float4*)(W + idx);
  }
  __syncthreads();
  int node = blockIdx.x * 128 + tid;
  bool valid = node < N_NODES;
  int nclamp = valid ? node : N_NODES - 1;
  const float* xrow = in + (size_t)nclamp * K;
  float acc[64];
  if (EPI == 0) {
#pragma unroll
    for (int d = 0; d < 64; ++d) acc[d] = 0.f;
  } else {
#pragma unroll
    for (int d4 = 0; d4 < 16; ++d4) {
      float4 b4 = *(const float4*)(bias + d4 * 4);
      acc[d4 * 4 + 0] = b4.x; acc[d4 * 4 + 1] = b4.y;
      acc[d4 * 4 + 2] = b4.z; acc[d4 * 4 + 3] = b4.w;
    }
  }
  for (int c = 0; c < K / 16; ++c) {
    float xb[16];
#pragma unroll
    for (int q = 0; q < 4; ++q) {
      float4 v = *(const float4*)(xrow + c * 16 + q * 4);
      xb[q * 4 + 0] = v.x; xb[q * 4 + 1] = v.y;
      xb[q * 4 + 2] = v.z; xb[q * 4 + 3] = v.w;
    }
    if (PRE == 1) {
#pragma unroll
      for (int q = 0; q < 4; ++q) {
        float4 bav = *(const float4*)(pba + c * 16 + q * 4);
        float4 gv = *(const float4*)(pg + c * 16 + q * 4);
        float4 bev = *(const float4*)(pbe + c * 16 + q * 4);
        xb[q * 4 + 0] = relu(fmaf((xb[q * 4 + 0] + bav.x) * BN_SCALE, gv.x, bev.x));
        xb[q * 4 + 1] = relu(fmaf((xb[q * 4 + 1] + bav.y) * BN_SCALE, gv.y, bev.y));
        xb[q * 4 + 2] = relu(fmaf((xb[q * 4 + 2] + bav.z) * BN_SCALE, gv.z, bev.z));
        xb[q * 4 + 3] = relu(fmaf((xb[q * 4 + 3] + bav.w) * BN_SCALE, gv.w, bev.w));
      }
    }
    const float* wc = lw + c * 16 * 64;
#pragma unroll
    for (int kk = 0; kk < 16; ++kk) {
      float xk = xb[kk];
#pragma unroll
      for (int d4 = 0; d4 < 16; ++d4) {
        float4 w4 = *(const float4*)(wc + kk * 64 + d4 * 4);
        acc[d4 * 4 + 0] = fmaf(xk, w4.x, acc[d4 * 4 + 0]);
        acc[d4 * 4 + 1] = fmaf(xk, w4.y, acc[d4 * 4 + 1]);
        acc[d4 * 4 + 2] = fmaf(xk, w4.z, acc[d4 * 4 + 2]);
        acc[d4 * 4 + 3] = fmaf(xk, w4.w, acc[d4 * 4 + 3]);
      }
    }
  }
  if (valid) {
#pragma unroll
    for (int d4 = 0; d4 < 16; ++d4) {
      float4 r = {acc[d4 * 4 + 0], acc[d4 * 4 + 1], acc[d4 * 4 + 2], acc[d4 * 4 + 3]};
      if (EPI == 1) {
        r.x = relu(r.x); r.y = relu(r.y); r.z = relu(r.z); r.w = relu(r.w);
      } else if (EPI == 2) {
        float4 g4 = *(const float4*)(g + d4 * 4);
        float4 be4 = *(const float4*)(be + d4 * 4);
        r.x = relu(fmaf(r.x * BN_SCALE, g4.x, be4.x));
        r.y = relu(fmaf(r.y * BN_SCALE, g4.y, be4.y));
        r.z = relu(fmaf(r.z * BN_SCALE, g4.z, be4.z));
        r.w = relu(fmaf(r.w * BN_SCALE, g4.w, be4.w));
      }
      if (BF) {
        uint2 p;
        p.x = (unsigned int)f2bf(r.x) | ((unsigned int)f2bf(r.y) << 16);
        p.y = (unsigned int)f2bf(r.z) | ((unsigned int)f2bf(r.w) << 16);
        *(uint2*)(outb + (size_t)node * 64 + d4 * 4) = p;
      } else {
        *(float4*)(outf + (size_t)node * 64 + d4 * 4) = r;
      }
    }
  }
}

// ---------------- pool: bf16 h rows, fp32 accumulate ----------------
__global__ __launch_bounds__(256) void pool_kernel(const unsigned short* __restrict__ hb,
                                                   const int* __restrict__ batch,
                                                   float* __restrict__ hp) {
  const int CH = (N_NODES + 1023) / 1024;
  int w = (blockIdx.x * blockDim.x + threadIdx.x) >> 6;
  int lane = threadIdx.x & 63;
  int start = w * CH;
  if (start >= N_NODES) return;
  int end = start + CH;
  if (end > N_NODES) end = N_NODES;
  int cur = batch[start];
  float acc = 0.f;
  for (int n = start; n < end; ++n) {
    int b = batch[n];
    if (b != cur) {
      atomicAdd(&hp[cur * 64 + lane], acc);
      acc = 0.f;
      cur = b;
    }
    acc += bf2f(hb[(size_t)n * 64 + lane]);
  }
  atomicAdd(&hp[cur * 64 + lane], acc);
}

// ---------------- classifier ----------------
__global__ __launch_bounds__(64) void cls_kernel(const float* __restrict__ hp,
                                                 const float* __restrict__ Wl1,
                                                 const float* __restrict__ bl1,
                                                 const float* __restrict__ Wl2,
                                                 const float* __restrict__ bl2,
                                                 float* __restrict__ out) {
  int g = blockIdx.x;
  int d = threadIdx.x;
  const float* hrow = hp + g * 64;
  float acc = bl1[d];
#pragma unroll 8
  for (int k = 0; k < 64; ++k) {
    float v = hrow[k];
    float w = Wl1[k * 64 + d] + Wl1[(64 + k) * 64 + d] + Wl1[(128 + k) * 64 + d];
    acc = fmaf(v, w, acc);
  }
  float t = relu(acc);
  float p0 = t * Wl2[d * 2 + 0];
  float p1 = t * Wl2[d * 2 + 1];
#pragma unroll
  for (int off = 32; off > 0; off >>= 1) {
    p0 += __shfl_xor(p0, off, 64);
    p1 += __shfl_xor(p1, off, 64);
  }
  if (d == 0) {
    float z0 = p0 + bl2[0];
    float z1 = p1 + bl2[1];
    float m = fmaxf(z0, z1);
    float lse = m + logf(expf(z0 - m) + expf(z1 - m));
    out[g * 2 + 0] = z0 - lse;
    out[g * 2 + 1] = z1 - lse;
  }
}

extern "C" void kernel_launch(void* const* d_in, const int* in_sizes, int n_in,
                              void* d_out, int out_size, void* d_ws, size_t ws_size,
                              hipStream_t stream) {
  const float* x   = (const float*)d_in[0];
  const int*   ei  = (const int*)d_in[1];
  const int*   bat = (const int*)d_in[2];
  const float* W0a = (const float*)d_in[3];
  const float* b0a = (const float*)d_in[4];
  const float* g0  = (const float*)d_in[5];
  const float* be0 = (const float*)d_in[6];
  const float* W0b = (const float*)d_in[7];
  const float* b0b = (const float*)d_in[8];
  const float* Wsa = (const float*)d_in[9];
  const float* bsa = (const float*)d_in[10];
  const float* gs  = (const float*)d_in[11];
  const float* bes = (const float*)d_in[12];
  const float* Wsb = (const float*)d_in[13];
  const float* bsb = (const float*)d_in[14];
  const float* Wl1 = (const float*)d_in[15];
  const float* bl1 = (const float*)d_in[16];
  const float* Wl2 = (const float*)d_in[17];
  const float* bl2 = (const float*)d_in[18];
  const int* src = ei;
  const int* dst = ei + N_EDGES;

  char* ws = (char*)d_ws;
  size_t off = 0;
  auto alloc = [&](size_t bytes) { void* p = ws + off; off += (bytes + 255) & ~255ull; return p; };
  int* rp      = (int*)alloc((size_t)(N_NODES + 1) * 4);
  int* cnt     = (int*)alloc((size_t)NBLK * NBUCKET * 4);
  int* tot     = (int*)alloc((size_t)NBUCKET * 4);
  int* bktbase = (int*)alloc((size_t)NBUCKET * 4);
  int* ci      = (int*)alloc((size_t)N_EDGES * 4);
  float* bufZ  = (float*)alloc((size_t)N_NODES * 64 * 4);
  unsigned short* hb = (unsigned short*)alloc((size_t)N_NODES * 64 * 2);
  float* hp    = (float*)alloc((size_t)N_GRAPHS * 64 * 4);
  int* bktbuf  = (int*)bufZ;  // alias: consumed before bufZ first written

  hipMemsetAsync(hp, 0, (size_t)N_GRAPHS * 64 * 4, stream);

  edge_count<<<NBLK, 256, 0, stream>>>(dst, cnt);
  col_scan<<<NBUCKET, NBLK, 0, stream>>>(cnt, tot);
  base_scan<<<1, 256, 0, stream>>>(tot, bktbase);
  edge_place<<<NBLK, 256, 0, stream>>>(src, dst, cnt, bktbase, bktbuf);
  bucket_sort<<<NBUCKET, 256, 0, stream>>>(tot, bktbase, bktbuf, rp, ci);

  const int GB = (N_NODES + 127) / 128;    // 782
  const int AB = (N_NODES + 3) / 4;        // 25000

  // conv0: proj (K=128) -> bf16 h0; agg; W0b-GEMM with fused pre-BN-relu -> bf16 h1
  gemm_kernel<128, 0, 0, 1><<<GB, 128, 0, stream>>>(
      x, W0a, nullptr, nullptr, nullptr, nullptr, nullptr, nullptr, nullptr, hb);
  agg_kernel<<<AB, 256, 0, stream>>>(hb, rp, ci, bufZ);
  gemm_kernel<64, 1, 1, 1><<<GB, 128, 0, stream>>>(
      bufZ, W0b, b0a, g0, be0, b0b, nullptr, nullptr, nullptr, hb);

  for (int l = 0; l < 2; ++l) {
    agg_kernel<<<AB, 256, 0, stream>>>(hb, rp, ci, bufZ);
    gemm_kernel<64, 0, 2, 0><<<GB, 128, 0, stream>>>(
        bufZ, Wsa + l * 4096, nullptr, nullptr, nullptr,
        bsa + l * 64, gs + l * 64, bes + l * 64, bufZ, nullptr);  // in-place fp32
    gemm_kernel<64, 0, 1, 1><<<GB, 128, 0, stream>>>(
        bufZ, Wsb + l * 4096, nullptr, nullptr, nullptr,
        bsb + l * 64, nullptr, nullptr, nullptr, hb);
  }

  pool_kernel<<<256, 256, 0, stream>>>(hb, bat, hp);
  cls_kernel<<<N_GRAPHS, 64, 0, stream>>>(hp, Wl1, bl1, Wl2, bl2, (float*)d_out);
}

// Round 8
// 435.240 us; speedup vs baseline: 1.4823x; 1.0171x over previous
//
#include <hip/hip_runtime.h>

#define N_NODES 100000
#define N_EDGES 1600000
#define IN_DIM 128
#define DIM_H 64
#define N_GRAPHS 64

#define BKT_BITS 9
#define BKT_SIZE 512
#define NBUCKET ((N_NODES + BKT_SIZE - 1) / BKT_SIZE)  /* 196 */
#define NBLK 256
#define EPB ((N_EDGES + NBLK - 1) / NBLK)              /* 6250 */

__device__ __forceinline__ float relu(float v) { return v > 0.f ? v : 0.f; }
#define BN_SCALE 0.99999500003749968f  /* 1/sqrt(1+1e-5) */

__device__ __forceinline__ float bf2f(unsigned short u) {
  return __uint_as_float(((unsigned int)u) << 16);
}
__device__ __forceinline__ unsigned short f2bf(float f) {
  unsigned int u = __float_as_uint(f);
  u += 0x7FFFu + ((u >> 16) & 1u);   // round-to-nearest-even
  return (unsigned short)(u >> 16);
}

// ---------------- CSR build: 3-phase block-private counting sort ----------------
__global__ __launch_bounds__(256) void edge_count(const int* __restrict__ dst,
                                                  int* __restrict__ cnt) {
  __shared__ int hist[NBUCKET];
  int tid = threadIdx.x, blk = blockIdx.x;
  if (tid < NBUCKET) hist[tid] = 0;
  __syncthreads();
  int beg = blk * EPB, end = beg + EPB > N_EDGES ? N_EDGES : beg + EPB;
  for (int i = beg + tid; i < end; i += 256) atomicAdd(&hist[dst[i] >> BKT_BITS], 1);
  __syncthreads();
  if (tid < NBUCKET) cnt[blk * NBUCKET + tid] = hist[tid];
}

__global__ __launch_bounds__(256) void col_scan(int* __restrict__ cnt,
                                                int* __restrict__ tot) {
  __shared__ int sd[NBLK];
  int b = blockIdx.x, tid = threadIdx.x;
  int v = cnt[tid * NBUCKET + b];
  sd[tid] = v;
  __syncthreads();
  for (int off = 1; off < NBLK; off <<= 1) {
    int t = (tid >= off) ? sd[tid - off] : 0;
    __syncthreads();
    sd[tid] += t;
    __syncthreads();
  }
  cnt[tid * NBUCKET + b] = sd[tid] - v;
  if (tid == NBLK - 1) tot[b] = sd[tid];
}

__global__ void base_scan(const int* __restrict__ tot, int* __restrict__ base) {
  __shared__ int sd[256];
  int tid = threadIdx.x;
  int v = (tid < NBUCKET) ? tot[tid] : 0;
  sd[tid] = v;
  __syncthreads();
  for (int off = 1; off < 256; off <<= 1) {
    int t = (tid >= off) ? sd[tid - off] : 0;
    __syncthreads();
    sd[tid] += t;
    __syncthreads();
  }
  if (tid < NBUCKET) base[tid] = sd[tid] - v;
}

__global__ __launch_bounds__(256) void edge_place(const int* __restrict__ src,
                                                  const int* __restrict__ dst,
                                                  const int* __restrict__ cnt,
                                                  const int* __restrict__ base,
                                                  int* __restrict__ bktbuf) {
  __shared__ int curs[NBUCKET];
  int tid = threadIdx.x, blk = blockIdx.x;
  if (tid < NBUCKET) curs[tid] = base[tid] + cnt[blk * NBUCKET + tid];
  __syncthreads();
  int beg = blk * EPB, end = beg + EPB > N_EDGES ? N_EDGES : beg + EPB;
  for (int i = beg + tid; i < end; i += 256) {
    int d = dst[i];
    int b = d >> BKT_BITS;
    int pos = atomicAdd(&curs[b], 1);
    bktbuf[pos] = src[i] | ((d & (BKT_SIZE - 1)) << 17);
  }
}

__global__ __launch_bounds__(256) void bucket_sort(const int* __restrict__ tot,
                                                   const int* __restrict__ bktbase,
                                                   const int* __restrict__ bktbuf,
                                                   int* __restrict__ rp,
                                                   int* __restrict__ ci) {
  __shared__ int hist[BKT_SIZE];
  __shared__ int partial[256];
  int b = blockIdx.x;
  int tid = threadIdx.x;
  int nb = tot[b];
  int base = bktbase[b];
  const int* buf = bktbuf + base;
  hist[tid] = 0;
  hist[tid + 256] = 0;
  __syncthreads();
  for (int i = tid; i < nb; i += 256) atomicAdd(&hist[buf[i] >> 17], 1);
  __syncthreads();
  int v0 = hist[2 * tid], v1 = hist[2 * tid + 1];
  int s = v0 + v1;
  partial[tid] = s;
  __syncthreads();
  for (int off = 1; off < 256; off <<= 1) {
    int t = (tid >= off) ? partial[tid - off] : 0;
    __syncthreads();
    partial[tid] += t;
    __syncthreads();
  }
  int excl = partial[tid] - s;
  int node0 = b * BKT_SIZE + 2 * tid;
  if (node0 < N_NODES) rp[node0] = base + excl;
  if (node0 + 1 < N_NODES) rp[node0 + 1] = base + excl + v0;
  __syncthreads();
  hist[2 * tid] = excl;
  hist[2 * tid + 1] = excl + v0;
  __syncthreads();
  for (int i = tid; i < nb; i += 256) {
    int p = buf[i];
    int pos = atomicAdd(&hist[p >> 17], 1);
    ci[base + pos] = p & 0x1FFFF;
  }
  if (b == 0 && tid == 0) rp[N_NODES] = N_EDGES;
}

// ---------------- aggregation: bf16 gathers, fp32 accumulate, bf16 out ----------------
__global__ __launch_bounds__(256) void agg_kernel(const unsigned short* __restrict__ hb,
                                                  const int* __restrict__ rp,
                                                  const int* __restrict__ ci,
                                                  unsigned short* __restrict__ zb) {
  int wid = (blockIdx.x * 256 + threadIdx.x) >> 6;
  if (wid >= N_NODES) return;
  int lane = threadIdx.x & 63;
  int eg = lane >> 4;        // edge subgroup 0..3
  int dq = lane & 15;        // 4-dim slot within row
  int beg = rp[wid], end = rp[wid + 1];
  float a0 = 0.f, a1 = 0.f, a2 = 0.f, a3 = 0.f;
  float b0 = 0.f, b1 = 0.f, b2 = 0.f, b3 = 0.f;
  int e = beg;
  for (; e + 8 <= end; e += 8) {
    int i0 = ci[e + eg];
    int i1 = ci[e + 4 + eg];
    ushort4 v0 = *(const ushort4*)(hb + (size_t)i0 * 64 + dq * 4);
    ushort4 v1 = *(const ushort4*)(hb + (size_t)i1 * 64 + dq * 4);
    a0 += bf2f(v0.x); a1 += bf2f(v0.y); a2 += bf2f(v0.z); a3 += bf2f(v0.w);
    b0 += bf2f(v1.x); b1 += bf2f(v1.y); b2 += bf2f(v1.z); b3 += bf2f(v1.w);
  }
  for (; e < end; e += 4) {
    if (e + eg < end) {
      ushort4 v0 = *(const ushort4*)(hb + (size_t)ci[e + eg] * 64 + dq * 4);
      a0 += bf2f(v0.x); a1 += bf2f(v0.y); a2 += bf2f(v0.z); a3 += bf2f(v0.w);
    }
  }
  a0 += b0; a1 += b1; a2 += b2; a3 += b3;
  a0 += __shfl_xor(a0, 16, 64); a1 += __shfl_xor(a1, 16, 64);
  a2 += __shfl_xor(a2, 16, 64); a3 += __shfl_xor(a3, 16, 64);
  a0 += __shfl_xor(a0, 32, 64); a1 += __shfl_xor(a1, 32, 64);
  a2 += __shfl_xor(a2, 32, 64); a3 += __shfl_xor(a3, 32, 64);
  if (eg == 0) {
    ushort4 s = *(const ushort4*)(hb + (size_t)wid * 64 + dq * 4);
    ushort4 o;
    o.x = f2bf(a0 + bf2f(s.x));
    o.y = f2bf(a1 + bf2f(s.y));
    o.z = f2bf(a2 + bf2f(s.z));
    o.w = f2bf(a3 + bf2f(s.w));
    *(ushort4*)(zb + (size_t)wid * 64 + dq * 4) = o;
  }
}

// ---------------- row-local GEMM: 2 threads/node (32 outs each), W in LDS ----------------
// K inner dim. BFIN: input rows bf16 (inb) else fp32 (inf). PRE: 1 = relu((x+pba)*C*pg+pbe)
// on input. EPI: 0 none (no bias), 1 relu(acc+bias), 2 relu((acc+bias)*C*g+be). Out bf16.
template <int K, int BFIN, int PRE, int EPI>
__global__ __launch_bounds__(256) void gemm_kernel(const float* __restrict__ inf,
                                                   const unsigned short* __restrict__ inb,
                                                   const float* __restrict__ W,
                                                   const float* __restrict__ pba,
                                                   const float* __restrict__ pg,
                                                   const float* __restrict__ pbe,
                                                   const float* __restrict__ bias,
                                                   const float* __restrict__ g,
                                                   const float* __restrict__ be,
                                                   unsigned short* __restrict__ outb) {
  __shared__ float lw[K * 64];
  int tid = threadIdx.x;
#pragma unroll
  for (int it = 0; it < K * 64 / 1024; ++it) {
    int idx = (tid + it * 256) * 4;
    *(float4*)(lw + idx) = *(const float4*)(W + idx);
  }
  __syncthreads();
  int node = blockIdx.x * 128 + (tid >> 1);
  int obase = (tid & 1) * 32;
  bool valid = node < N_NODES;
  int nclamp = valid ? node : N_NODES - 1;
  float acc[32];
  if (EPI == 0) {
#pragma unroll
    for (int d = 0; d < 32; ++d) acc[d] = 0.f;
  } else {
#pragma unroll
    for (int d4 = 0; d4 < 8; ++d4) {
      float4 b4 = *(const float4*)(bias + obase + d4 * 4);
      acc[d4 * 4 + 0] = b4.x; acc[d4 * 4 + 1] = b4.y;
      acc[d4 * 4 + 2] = b4.z; acc[d4 * 4 + 3] = b4.w;
    }
  }
  const float* xrowf = inf + (size_t)nclamp * K;
  const unsigned short* xrowb = inb + (size_t)nclamp * K;
  for (int c = 0; c < K / 16; ++c) {
    float xb[16];
    if (BFIN) {
#pragma unroll
      for (int q = 0; q < 2; ++q) {
        uint4 u = *(const uint4*)(xrowb + c * 16 + q * 8);
        xb[q * 8 + 0] = __uint_as_float(u.x << 16);
        xb[q * 8 + 1] = __uint_as_float(u.x & 0xFFFF0000u);
        xb[q * 8 + 2] = __uint_as_float(u.y << 16);
        xb[q * 8 + 3] = __uint_as_float(u.y & 0xFFFF0000u);
        xb[q * 8 + 4] = __uint_as_float(u.z << 16);
        xb[q * 8 + 5] = __uint_as_float(u.z & 0xFFFF0000u);
        xb[q * 8 + 6] = __uint_as_float(u.w << 16);
        xb[q * 8 + 7] = __uint_as_float(u.w & 0xFFFF0000u);
      }
    } else {
#pragma unroll
      for (int q = 0; q < 4; ++q) {
        float4 v = *(const float4*)(xrowf + c * 16 + q * 4);
        xb[q * 4 + 0] = v.x; xb[q * 4 + 1] = v.y;
        xb[q * 4 + 2] = v.z; xb[q * 4 + 3] = v.w;
      }
    }
    if (PRE == 1) {
#pragma unroll
      for (int q = 0; q < 4; ++q) {
        float4 bav = *(const float4*)(pba + c * 16 + q * 4);
        float4 gv = *(const float4*)(pg + c * 16 + q * 4);
        float4 bev = *(const float4*)(pbe + c * 16 + q * 4);
        xb[q * 4 + 0] = relu(fmaf((xb[q * 4 + 0] + bav.x) * BN_SCALE, gv.x, bev.x));
        xb[q * 4 + 1] = relu(fmaf((xb[q * 4 + 1] + bav.y) * BN_SCALE, gv.y, bev.y));
        xb[q * 4 + 2] = relu(fmaf((xb[q * 4 + 2] + bav.z) * BN_SCALE, gv.z, bev.z));
        xb[q * 4 + 3] = relu(fmaf((xb[q * 4 + 3] + bav.w) * BN_SCALE, gv.w, bev.w));
      }
    }
    const float* wc = lw + c * 16 * 64 + obase;
#pragma unroll
    for (int kk = 0; kk < 16; ++kk) {
      float xk = xb[kk];
#pragma unroll
      for (int d4 = 0; d4 < 8; ++d4) {
        float4 w4 = *(const float4*)(wc + kk * 64 + d4 * 4);
        acc[d4 * 4 + 0] = fmaf(xk, w4.x, acc[d4 * 4 + 0]);
        acc[d4 * 4 + 1] = fmaf(xk, w4.y, acc[d4 * 4 + 1]);
        acc[d4 * 4 + 2] = fmaf(xk, w4.z, acc[d4 * 4 + 2]);
        acc[d4 * 4 + 3] = fmaf(xk, w4.w, acc[d4 * 4 + 3]);
      }
    }
  }
  if (valid) {
#pragma unroll
    for (int d4 = 0; d4 < 8; ++d4) {
      float4 r = {acc[d4 * 4 + 0], acc[d4 * 4 + 1], acc[d4 * 4 + 2], acc[d4 * 4 + 3]};
      if (EPI == 1) {
        r.x = relu(r.x); r.y = relu(r.y); r.z = relu(r.z); r.w = relu(r.w);
      } else if (EPI == 2) {
        float4 g4 = *(const float4*)(g + obase + d4 * 4);
        float4 be4 = *(const float4*)(be + obase + d4 * 4);
        r.x = relu(fmaf(r.x * BN_SCALE, g4.x, be4.x));
        r.y = relu(fmaf(r.y * BN_SCALE, g4.y, be4.y));
        r.z = relu(fmaf(r.z * BN_SCALE, g4.z, be4.z));
        r.w = relu(fmaf(r.w * BN_SCALE, g4.w, be4.w));
      }
      uint2 p;
      p.x = (unsigned int)f2bf(r.x) | ((unsigned int)f2bf(r.y) << 16);
      p.y = (unsigned int)f2bf(r.z) | ((unsigned int)f2bf(r.w) << 16);
      *(uint2*)(outb + (size_t)node * 64 + obase + d4 * 4) = p;
    }
  }
}

// ---------------- pool: bf16 h rows, fp32 accumulate ----------------
__global__ __launch_bounds__(256) void pool_kernel(const unsigned short* __restrict__ hb,
                                                   const int* __restrict__ batch,
                                                   float* __restrict__ hp) {
  const int CH = (N_NODES + 1023) / 1024;
  int w = (blockIdx.x * blockDim.x + threadIdx.x) >> 6;
  int lane = threadIdx.x & 63;
  int start = w * CH;
  if (start >= N_NODES) return;
  int end = start + CH;
  if (end > N_NODES) end = N_NODES;
  int cur = batch[start];
  float acc = 0.f;
  for (int n = start; n < end; ++n) {
    int b = batch[n];
    if (b != cur) {
      atomicAdd(&hp[cur * 64 + lane], acc);
      acc = 0.f;
      cur = b;
    }
    acc += bf2f(hb[(size_t)n * 64 + lane]);
  }
  atomicAdd(&hp[cur * 64 + lane], acc);
}

// ---------------- classifier ----------------
__global__ __launch_bounds__(64) void cls_kernel(const float* __restrict__ hp,
                                                 const float* __restrict__ Wl1,
                                                 const float* __restrict__ bl1,
                                                 const float* __restrict__ Wl2,
                                                 const float* __restrict__ bl2,
                                                 float* __restrict__ out) {
  int g = blockIdx.x;
  int d = threadIdx.x;
  const float* hrow = hp + g * 64;
  float acc = bl1[d];
#pragma unroll 8
  for (int k = 0; k < 64; ++k) {
    float v = hrow[k];
    float w = Wl1[k * 64 + d] + Wl1[(64 + k) * 64 + d] + Wl1[(128 + k) * 64 + d];
    acc = fmaf(v, w, acc);
  }
  float t = relu(acc);
  float p0 = t * Wl2[d * 2 + 0];
  float p1 = t * Wl2[d * 2 + 1];
#pragma unroll
  for (int off = 32; off > 0; off >>= 1) {
    p0 += __shfl_xor(p0, off, 64);
    p1 += __shfl_xor(p1, off, 64);
  }
  if (d == 0) {
    float z0 = p0 + bl2[0];
    float z1 = p1 + bl2[1];
    float m = fmaxf(z0, z1);
    float lse = m + logf(expf(z0 - m) + expf(z1 - m));
    out[g * 2 + 0] = z0 - lse;
    out[g * 2 + 1] = z1 - lse;
  }
}

extern "C" void kernel_launch(void* const* d_in, const int* in_sizes, int n_in,
                              void* d_out, int out_size, void* d_ws, size_t ws_size,
                              hipStream_t stream) {
  const float* x   = (const float*)d_in[0];
  const int*   ei  = (const int*)d_in[1];
  const int*   bat = (const int*)d_in[2];
  const float* W0a = (const float*)d_in[3];
  const float* b0a = (const float*)d_in[4];
  const float* g0  = (const float*)d_in[5];
  const float* be0 = (const float*)d_in[6];
  const float* W0b = (const float*)d_in[7];
  const float* b0b = (const float*)d_in[8];
  const float* Wsa = (const float*)d_in[9];
  const float* bsa = (const float*)d_in[10];
  const float* gs  = (const float*)d_in[11];
  const float* bes = (const float*)d_in[12];
  const float* Wsb = (const float*)d_in[13];
  const float* bsb = (const float*)d_in[14];
  const float* Wl1 = (const float*)d_in[15];
  const float* bl1 = (const float*)d_in[16];
  const float* Wl2 = (const float*)d_in[17];
  const float* bl2 = (const float*)d_in[18];
  const int* src = ei;
  const int* dst = ei + N_EDGES;

  char* ws = (char*)d_ws;
  size_t off = 0;
  auto alloc = [&](size_t bytes) { void* p = ws + off; off += (bytes + 255) & ~255ull; return p; };
  int* rp      = (int*)alloc((size_t)(N_NODES + 1) * 4);
  int* cnt     = (int*)alloc((size_t)NBLK * NBUCKET * 4);
  int* tot     = (int*)alloc((size_t)NBUCKET * 4);
  int* bktbase = (int*)alloc((size_t)NBUCKET * 4);
  int* ci      = (int*)alloc((size_t)N_EDGES * 4);
  unsigned short* zb = (unsigned short*)alloc((size_t)N_NODES * 64 * 2);
  unsigned short* hb = (unsigned short*)alloc((size_t)N_NODES * 64 * 2);
  float* hp    = (float*)alloc((size_t)N_GRAPHS * 64 * 4);
  int* bktbuf  = (int*)zb;  // alias: 6.4 MB bucket buffer consumed before zb first written

  hipMemsetAsync(hp, 0, (size_t)N_GRAPHS * 64 * 4, stream);

  edge_count<<<NBLK, 256, 0, stream>>>(dst, cnt);
  col_scan<<<NBUCKET, NBLK, 0, stream>>>(cnt, tot);
  base_scan<<<1, 256, 0, stream>>>(tot, bktbase);
  edge_place<<<NBLK, 256, 0, stream>>>(src, dst, cnt, bktbase, bktbuf);
  bucket_sort<<<NBUCKET, 256, 0, stream>>>(tot, bktbase, bktbuf, rp, ci);

  const int GB = (N_NODES + 127) / 128;    // 782 blocks (256 thr = 128 nodes x 2)
  const int AB = (N_NODES + 3) / 4;        // 25000

  // conv0: proj (K=128, fp32 in) -> bf16 h; agg -> bf16 z; W0b-GEMM (pre BN-relu) -> bf16 h
  gemm_kernel<128, 0, 0, 0><<<GB, 256, 0, stream>>>(
      x, nullptr, W0a, nullptr, nullptr, nullptr, nullptr, nullptr, nullptr, hb);
  agg_kernel<<<AB, 256, 0, stream>>>(hb, rp, ci, zb);
  gemm_kernel<64, 1, 1, 1><<<GB, 256, 0, stream>>>(
      nullptr, zb, W0b, b0a, g0, be0, b0b, nullptr, nullptr, hb);

  for (int l = 0; l < 2; ++l) {
    agg_kernel<<<AB, 256, 0, stream>>>(hb, rp, ci, zb);
    gemm_kernel<64, 1, 0, 2><<<GB, 256, 0, stream>>>(
        nullptr, zb, Wsa + l * 4096, nullptr, nullptr, nullptr,
        bsa + l * 64, gs + l * 64, bes + l * 64, zb);  // in-place bf16 (row-local)
    gemm_kernel<64, 1, 0, 1><<<GB, 256, 0, stream>>>(
        nullptr, zb, Wsb + l * 4096, nullptr, nullptr, nullptr,
        bsb + l * 64, nullptr, nullptr, hb);
  }

  pool_kernel<<<256, 256, 0, stream>>>(hb, bat, hp);
  cls_kernel<<<N_GRAPHS, 64, 0, stream>>>(hp, Wl1, bl1, Wl2, bl2, (float*)d_out);
}

// Round 9
// 411.017 us; speedup vs baseline: 1.5696x; 1.0589x over previous
//
#include <hip/hip_runtime.h>

#define N_NODES 100000
#define N_EDGES 1600000
#define IN_DIM 128
#define DIM_H 64
#define N_GRAPHS 64

#define BKT_BITS 9
#define BKT_SIZE 512
#define NBUCKET ((N_NODES + BKT_SIZE - 1) / BKT_SIZE)  /* 196 */
#define NBLK 256
#define EPB ((N_EDGES + NBLK - 1) / NBLK)              /* 6250 */

__device__ __forceinline__ float relu(float v) { return v > 0.f ? v : 0.f; }
#define BN_SCALE 0.99999500003749968f  /* 1/sqrt(1+1e-5) */

__device__ __forceinline__ float bf2f(unsigned short u) {
  return __uint_as_float(((unsigned int)u) << 16);
}
__device__ __forceinline__ float bflo(unsigned int u) {
  return __uint_as_float(u << 16);
}
__device__ __forceinline__ float bfhi(unsigned int u) {
  return __uint_as_float(u & 0xFFFF0000u);
}
__device__ __forceinline__ unsigned short f2bf(float f) {
  unsigned int u = __float_as_uint(f);
  u += 0x7FFFu + ((u >> 16) & 1u);   // round-to-nearest-even
  return (unsigned short)(u >> 16);
}

// ---------------- CSR build: 3-phase block-private counting sort ----------------
__global__ __launch_bounds__(256) void edge_count(const int* __restrict__ dst,
                                                  int* __restrict__ cnt) {
  __shared__ int hist[NBUCKET];
  int tid = threadIdx.x, blk = blockIdx.x;
  if (tid < NBUCKET) hist[tid] = 0;
  __syncthreads();
  int beg = blk * EPB, end = beg + EPB > N_EDGES ? N_EDGES : beg + EPB;
  for (int i = beg + tid; i < end; i += 256) atomicAdd(&hist[dst[i] >> BKT_BITS], 1);
  __syncthreads();
  if (tid < NBUCKET) cnt[blk * NBUCKET + tid] = hist[tid];
}

__global__ __launch_bounds__(256) void col_scan(int* __restrict__ cnt,
                                                int* __restrict__ tot) {
  __shared__ int sd[NBLK];
  int b = blockIdx.x, tid = threadIdx.x;
  int v = cnt[tid * NBUCKET + b];
  sd[tid] = v;
  __syncthreads();
  for (int off = 1; off < NBLK; off <<= 1) {
    int t = (tid >= off) ? sd[tid - off] : 0;
    __syncthreads();
    sd[tid] += t;
    __syncthreads();
  }
  cnt[tid * NBUCKET + b] = sd[tid] - v;
  if (tid == NBLK - 1) tot[b] = sd[tid];
}

__global__ void base_scan(const int* __restrict__ tot, int* __restrict__ base) {
  __shared__ int sd[256];
  int tid = threadIdx.x;
  int v = (tid < NBUCKET) ? tot[tid] : 0;
  sd[tid] = v;
  __syncthreads();
  for (int off = 1; off < 256; off <<= 1) {
    int t = (tid >= off) ? sd[tid - off] : 0;
    __syncthreads();
    sd[tid] += t;
    __syncthreads();
  }
  if (tid < NBUCKET) base[tid] = sd[tid] - v;
}

__global__ __launch_bounds__(256) void edge_place(const int* __restrict__ src,
                                                  const int* __restrict__ dst,
                                                  const int* __restrict__ cnt,
                                                  const int* __restrict__ base,
                                                  int* __restrict__ bktbuf) {
  __shared__ int curs[NBUCKET];
  int tid = threadIdx.x, blk = blockIdx.x;
  if (tid < NBUCKET) curs[tid] = base[tid] + cnt[blk * NBUCKET + tid];
  __syncthreads();
  int beg = blk * EPB, end = beg + EPB > N_EDGES ? N_EDGES : beg + EPB;
  for (int i = beg + tid; i < end; i += 256) {
    int d = dst[i];
    int b = d >> BKT_BITS;
    int pos = atomicAdd(&curs[b], 1);
    bktbuf[pos] = src[i] | ((d & (BKT_SIZE - 1)) << 17);
  }
}

__global__ __launch_bounds__(256) void bucket_sort(const int* __restrict__ tot,
                                                   const int* __restrict__ bktbase,
                                                   const int* __restrict__ bktbuf,
                                                   int* __restrict__ rp,
                                                   int* __restrict__ ci) {
  __shared__ int hist[BKT_SIZE];
  __shared__ int partial[256];
  int b = blockIdx.x;
  int tid = threadIdx.x;
  int nb = tot[b];
  int base = bktbase[b];
  const int* buf = bktbuf + base;
  hist[tid] = 0;
  hist[tid + 256] = 0;
  __syncthreads();
  for (int i = tid; i < nb; i += 256) atomicAdd(&hist[buf[i] >> 17], 1);
  __syncthreads();
  int v0 = hist[2 * tid], v1 = hist[2 * tid + 1];
  int s = v0 + v1;
  partial[tid] = s;
  __syncthreads();
  for (int off = 1; off < 256; off <<= 1) {
    int t = (tid >= off) ? partial[tid - off] : 0;
    __syncthreads();
    partial[tid] += t;
    __syncthreads();
  }
  int excl = partial[tid] - s;
  int node0 = b * BKT_SIZE + 2 * tid;
  if (node0 < N_NODES) rp[node0] = base + excl;
  if (node0 + 1 < N_NODES) rp[node0 + 1] = base + excl + v0;
  __syncthreads();
  hist[2 * tid] = excl;
  hist[2 * tid + 1] = excl + v0;
  __syncthreads();
  for (int i = tid; i < nb; i += 256) {
    int p = buf[i];
    int pos = atomicAdd(&hist[p >> 17], 1);
    ci[base + pos] = p & 0x1FFFF;
  }
  if (b == 0 && tid == 0) rp[N_NODES] = N_EDGES;
}

// ---------------- aggregation: bf16 gathers, fp32 accumulate, bf16 out ----------------
__global__ __launch_bounds__(256) void agg_kernel(const unsigned short* __restrict__ hb,
                                                  const int* __restrict__ rp,
                                                  const int* __restrict__ ci,
                                                  unsigned short* __restrict__ zb) {
  int wid = (blockIdx.x * 256 + threadIdx.x) >> 6;
  if (wid >= N_NODES) return;
  int lane = threadIdx.x & 63;
  int eg = lane >> 4;        // edge subgroup 0..3
  int dq = lane & 15;        // 4-dim slot within row
  int beg = rp[wid], end = rp[wid + 1];
  float a0 = 0.f, a1 = 0.f, a2 = 0.f, a3 = 0.f;
  float b0 = 0.f, b1 = 0.f, b2 = 0.f, b3 = 0.f;
  int e = beg;
  for (; e + 8 <= end; e += 8) {
    int i0 = ci[e + eg];
    int i1 = ci[e + 4 + eg];
    ushort4 v0 = *(const ushort4*)(hb + (size_t)i0 * 64 + dq * 4);
    ushort4 v1 = *(const ushort4*)(hb + (size_t)i1 * 64 + dq * 4);
    a0 += bf2f(v0.x); a1 += bf2f(v0.y); a2 += bf2f(v0.z); a3 += bf2f(v0.w);
    b0 += bf2f(v1.x); b1 += bf2f(v1.y); b2 += bf2f(v1.z); b3 += bf2f(v1.w);
  }
  for (; e < end; e += 4) {
    if (e + eg < end) {
      ushort4 v0 = *(const ushort4*)(hb + (size_t)ci[e + eg] * 64 + dq * 4);
      a0 += bf2f(v0.x); a1 += bf2f(v0.y); a2 += bf2f(v0.z); a3 += bf2f(v0.w);
    }
  }
  a0 += b0; a1 += b1; a2 += b2; a3 += b3;
  a0 += __shfl_xor(a0, 16, 64); a1 += __shfl_xor(a1, 16, 64);
  a2 += __shfl_xor(a2, 16, 64); a3 += __shfl_xor(a3, 16, 64);
  a0 += __shfl_xor(a0, 32, 64); a1 += __shfl_xor(a1, 32, 64);
  a2 += __shfl_xor(a2, 32, 64); a3 += __shfl_xor(a3, 32, 64);
  if (eg == 0) {
    ushort4 s = *(const ushort4*)(hb + (size_t)wid * 64 + dq * 4);
    ushort4 o;
    o.x = f2bf(a0 + bf2f(s.x));
    o.y = f2bf(a1 + bf2f(s.y));
    o.z = f2bf(a2 + bf2f(s.z));
    o.w = f2bf(a3 + bf2f(s.w));
    *(ushort4*)(zb + (size_t)wid * 64 + dq * 4) = o;
  }
}

// ---------------- row-local GEMM: 4 nodes x 16 outs per thread, W in LDS ----------------
// K inner dim. BFIN: input rows bf16 (inb) else fp32 (inf). PRE: 1 = relu((x+pba)*C*pg+pbe)
// on input. EPI: 0 none (no bias), 1 relu(acc+bias), 2 relu((acc+bias)*C*g+be). Out bf16.
// Threads sharing a node's rows (tid 4g..4g+3) are in one wave -> in-place is lockstep-safe.
template <int K, int BFIN, int PRE, int EPI>
__global__ __launch_bounds__(128) void gemm_kernel(const float* __restrict__ inf,
                                                   const unsigned short* __restrict__ inb,
                                                   const float* __restrict__ W,
                                                   const float* __restrict__ pba,
                                                   const float* __restrict__ pg,
                                                   const float* __restrict__ pbe,
                                                   const float* __restrict__ bias,
                                                   const float* __restrict__ g,
                                                   const float* __restrict__ be,
                                                   unsigned short* __restrict__ outb) {
  __shared__ float lw[K * 64];
  int tid = threadIdx.x;
#pragma unroll
  for (int it = 0; it < K * 64 / 512; ++it) {
    int idx = (tid + it * 128) * 4;
    *(float4*)(lw + idx) = *(const float4*)(W + idx);
  }
  __syncthreads();
  int grp = tid >> 2;                 // node group 0..31
  int obase = (tid & 3) * 16;         // out quarter
  int n0 = blockIdx.x * 128 + grp * 4;
  float acc[4][16];
  if (EPI == 0) {
#pragma unroll
    for (int i = 0; i < 4; ++i)
#pragma unroll
      for (int j = 0; j < 16; ++j) acc[i][j] = 0.f;
  } else {
    float4 b0 = *(const float4*)(bias + obase);
    float4 b1 = *(const float4*)(bias + obase + 4);
    float4 b2 = *(const float4*)(bias + obase + 8);
    float4 b3 = *(const float4*)(bias + obase + 12);
#pragma unroll
    for (int i = 0; i < 4; ++i) {
      acc[i][0] = b0.x;  acc[i][1] = b0.y;  acc[i][2] = b0.z;  acc[i][3] = b0.w;
      acc[i][4] = b1.x;  acc[i][5] = b1.y;  acc[i][6] = b1.z;  acc[i][7] = b1.w;
      acc[i][8] = b2.x;  acc[i][9] = b2.y;  acc[i][10] = b2.z; acc[i][11] = b2.w;
      acc[i][12] = b3.x; acc[i][13] = b3.y; acc[i][14] = b3.z; acc[i][15] = b3.w;
    }
  }
  for (int c = 0; c < K / 16; ++c) {
    float xf[4][16];
#pragma unroll
    for (int i = 0; i < 4; ++i) {
      int node = n0 + i;
      if (node >= N_NODES) node = N_NODES - 1;
      if (BFIN) {
        const unsigned short* xr = inb + (size_t)node * K + c * 16;
        uint4 u0 = *(const uint4*)(xr);
        uint4 u1 = *(const uint4*)(xr + 8);
        xf[i][0] = bflo(u0.x);  xf[i][1] = bfhi(u0.x);
        xf[i][2] = bflo(u0.y);  xf[i][3] = bfhi(u0.y);
        xf[i][4] = bflo(u0.z);  xf[i][5] = bfhi(u0.z);
        xf[i][6] = bflo(u0.w);  xf[i][7] = bfhi(u0.w);
        xf[i][8] = bflo(u1.x);  xf[i][9] = bfhi(u1.x);
        xf[i][10] = bflo(u1.y); xf[i][11] = bfhi(u1.y);
        xf[i][12] = bflo(u1.z); xf[i][13] = bfhi(u1.z);
        xf[i][14] = bflo(u1.w); xf[i][15] = bfhi(u1.w);
      } else {
        const float* xr = inf + (size_t)node * K + c * 16;
        float4 v0 = *(const float4*)(xr);
        float4 v1 = *(const float4*)(xr + 4);
        float4 v2 = *(const float4*)(xr + 8);
        float4 v3 = *(const float4*)(xr + 12);
        xf[i][0] = v0.x;  xf[i][1] = v0.y;  xf[i][2] = v0.z;  xf[i][3] = v0.w;
        xf[i][4] = v1.x;  xf[i][5] = v1.y;  xf[i][6] = v1.z;  xf[i][7] = v1.w;
        xf[i][8] = v2.x;  xf[i][9] = v2.y;  xf[i][10] = v2.z; xf[i][11] = v2.w;
        xf[i][12] = v3.x; xf[i][13] = v3.y; xf[i][14] = v3.z; xf[i][15] = v3.w;
      }
    }
    if (PRE == 1) {
      float pa[16], pgv[16], pbv[16];
#pragma unroll
      for (int q = 0; q < 4; ++q) {
        float4 a4 = *(const float4*)(pba + c * 16 + q * 4);
        float4 g4 = *(const float4*)(pg + c * 16 + q * 4);
        float4 b4 = *(const float4*)(pbe + c * 16 + q * 4);
        pa[q * 4 + 0] = a4.x; pa[q * 4 + 1] = a4.y; pa[q * 4 + 2] = a4.z; pa[q * 4 + 3] = a4.w;
        pgv[q * 4 + 0] = g4.x; pgv[q * 4 + 1] = g4.y; pgv[q * 4 + 2] = g4.z; pgv[q * 4 + 3] = g4.w;
        pbv[q * 4 + 0] = b4.x; pbv[q * 4 + 1] = b4.y; pbv[q * 4 + 2] = b4.z; pbv[q * 4 + 3] = b4.w;
      }
#pragma unroll
      for (int i = 0; i < 4; ++i)
#pragma unroll
        for (int j = 0; j < 16; ++j)
          xf[i][j] = relu(fmaf((xf[i][j] + pa[j]) * BN_SCALE, pgv[j], pbv[j]));
    }
    const float* wc = lw + c * 16 * 64 + obase;
#pragma unroll
    for (int kk = 0; kk < 16; ++kk) {
      float4 w0 = *(const float4*)(wc + kk * 64);
      float4 w1 = *(const float4*)(wc + kk * 64 + 4);
      float4 w2 = *(const float4*)(wc + kk * 64 + 8);
      float4 w3 = *(const float4*)(wc + kk * 64 + 12);
#pragma unroll
      for (int i = 0; i < 4; ++i) {
        float xk = xf[i][kk];
        acc[i][0] = fmaf(xk, w0.x, acc[i][0]);
        acc[i][1] = fmaf(xk, w0.y, acc[i][1]);
        acc[i][2] = fmaf(xk, w0.z, acc[i][2]);
        acc[i][3] = fmaf(xk, w0.w, acc[i][3]);
        acc[i][4] = fmaf(xk, w1.x, acc[i][4]);
        acc[i][5] = fmaf(xk, w1.y, acc[i][5]);
        acc[i][6] = fmaf(xk, w1.z, acc[i][6]);
        acc[i][7] = fmaf(xk, w1.w, acc[i][7]);
        acc[i][8] = fmaf(xk, w2.x, acc[i][8]);
        acc[i][9] = fmaf(xk, w2.y, acc[i][9]);
        acc[i][10] = fmaf(xk, w2.z, acc[i][10]);
        acc[i][11] = fmaf(xk, w2.w, acc[i][11]);
        acc[i][12] = fmaf(xk, w3.x, acc[i][12]);
        acc[i][13] = fmaf(xk, w3.y, acc[i][13]);
        acc[i][14] = fmaf(xk, w3.z, acc[i][14]);
        acc[i][15] = fmaf(xk, w3.w, acc[i][15]);
      }
    }
  }
  float g16[16], be16[16];
  if (EPI == 2) {
#pragma unroll
    for (int q = 0; q < 4; ++q) {
      float4 g4 = *(const float4*)(g + obase + q * 4);
      float4 b4 = *(const float4*)(be + obase + q * 4);
      g16[q * 4 + 0] = g4.x; g16[q * 4 + 1] = g4.y; g16[q * 4 + 2] = g4.z; g16[q * 4 + 3] = g4.w;
      be16[q * 4 + 0] = b4.x; be16[q * 4 + 1] = b4.y; be16[q * 4 + 2] = b4.z; be16[q * 4 + 3] = b4.w;
    }
  }
#pragma unroll
  for (int i = 0; i < 4; ++i) {
    int node = n0 + i;
    if (node < N_NODES) {
      float r[16];
#pragma unroll
      for (int j = 0; j < 16; ++j) {
        float v = acc[i][j];
        if (EPI == 1) v = relu(v);
        else if (EPI == 2) v = relu(fmaf(v * BN_SCALE, g16[j], be16[j]));
        r[j] = v;
      }
      uint4 p0, p1;
      p0.x = (unsigned int)f2bf(r[0]) | ((unsigned int)f2bf(r[1]) << 16);
      p0.y = (unsigned int)f2bf(r[2]) | ((unsigned int)f2bf(r[3]) << 16);
      p0.z = (unsigned int)f2bf(r[4]) | ((unsigned int)f2bf(r[5]) << 16);
      p0.w = (unsigned int)f2bf(r[6]) | ((unsigned int)f2bf(r[7]) << 16);
      p1.x = (unsigned int)f2bf(r[8]) | ((unsigned int)f2bf(r[9]) << 16);
      p1.y = (unsigned int)f2bf(r[10]) | ((unsigned int)f2bf(r[11]) << 16);
      p1.z = (unsigned int)f2bf(r[12]) | ((unsigned int)f2bf(r[13]) << 16);
      p1.w = (unsigned int)f2bf(r[14]) | ((unsigned int)f2bf(r[15]) << 16);
      *(uint4*)(outb + (size_t)node * 64 + obase) = p0;
      *(uint4*)(outb + (size_t)node * 64 + obase + 8) = p1;
    }
  }
}

// ---------------- pool: bf16 h rows, fp32 accumulate ----------------
__global__ __launch_bounds__(256) void pool_kernel(const unsigned short* __restrict__ hb,
                                                   const int* __restrict__ batch,
                                                   float* __restrict__ hp) {
  const int CH = (N_NODES + 1023) / 1024;
  int w = (blockIdx.x * blockDim.x + threadIdx.x) >> 6;
  int lane = threadIdx.x & 63;
  int start = w * CH;
  if (start >= N_NODES) return;
  int end = start + CH;
  if (end > N_NODES) end = N_NODES;
  int cur = batch[start];
  float acc = 0.f;
  for (int n = start; n < end; ++n) {
    int b = batch[n];
    if (b != cur) {
      atomicAdd(&hp[cur * 64 + lane], acc);
      acc = 0.f;
      cur = b;
    }
    acc += bf2f(hb[(size_t)n * 64 + lane]);
  }
  atomicAdd(&hp[cur * 64 + lane], acc);
}

// ---------------- classifier ----------------
__global__ __launch_bounds__(64) void cls_kernel(const float* __restrict__ hp,
                                                 const float* __restrict__ Wl1,
                                                 const float* __restrict__ bl1,
                                                 const float* __restrict__ Wl2,
                                                 const float* __restrict__ bl2,
                                                 float* __restrict__ out) {
  int g = blockIdx.x;
  int d = threadIdx.x;
  const float* hrow = hp + g * 64;
  float acc = bl1[d];
#pragma unroll 8
  for (int k = 0; k < 64; ++k) {
    float v = hrow[k];
    float w = Wl1[k * 64 + d] + Wl1[(64 + k) * 64 + d] + Wl1[(128 + k) * 64 + d];
    acc = fmaf(v, w, acc);
  }
  float t = relu(acc);
  float p0 = t * Wl2[d * 2 + 0];
  float p1 = t * Wl2[d * 2 + 1];
#pragma unroll
  for (int off = 32; off > 0; off >>= 1) {
    p0 += __shfl_xor(p0, off, 64);
    p1 += __shfl_xor(p1, off, 64);
  }
  if (d == 0) {
    float z0 = p0 + bl2[0];
    float z1 = p1 + bl2[1];
    float m = fmaxf(z0, z1);
    float lse = m + logf(expf(z0 - m) + expf(z1 - m));
    out[g * 2 + 0] = z0 - lse;
    out[g * 2 + 1] = z1 - lse;
  }
}

extern "C" void kernel_launch(void* const* d_in, const int* in_sizes, int n_in,
                              void* d_out, int out_size, void* d_ws, size_t ws_size,
                              hipStream_t stream) {
  const float* x   = (const float*)d_in[0];
  const int*   ei  = (const int*)d_in[1];
  const int*   bat = (const int*)d_in[2];
  const float* W0a = (const float*)d_in[3];
  const float* b0a = (const float*)d_in[4];
  const float* g0  = (const float*)d_in[5];
  const float* be0 = (const float*)d_in[6];
  const float* W0b = (const float*)d_in[7];
  const float* b0b = (const float*)d_in[8];
  const float* Wsa = (const float*)d_in[9];
  const float* bsa = (const float*)d_in[10];
  const float* gs  = (const float*)d_in[11];
  const float* bes = (const float*)d_in[12];
  const float* Wsb = (const float*)d_in[13];
  const float* bsb = (const float*)d_in[14];
  const float* Wl1 = (const float*)d_in[15];
  const float* bl1 = (const float*)d_in[16];
  const float* Wl2 = (const float*)d_in[17];
  const float* bl2 = (const float*)d_in[18];
  const int* src = ei;
  const int* dst = ei + N_EDGES;

  char* ws = (char*)d_ws;
  size_t off = 0;
  auto alloc = [&](size_t bytes) { void* p = ws + off; off += (bytes + 255) & ~255ull; return p; };
  int* rp      = (int*)alloc((size_t)(N_NODES + 1) * 4);
  int* cnt     = (int*)alloc((size_t)NBLK * NBUCKET * 4);
  int* tot     = (int*)alloc((size_t)NBUCKET * 4);
  int* bktbase = (int*)alloc((size_t)NBUCKET * 4);
  int* ci      = (int*)alloc((size_t)N_EDGES * 4);
  unsigned short* zb = (unsigned short*)alloc((size_t)N_NODES * 64 * 2);
  unsigned short* hb = (unsigned short*)alloc((size_t)N_NODES * 64 * 2);
  float* hp    = (float*)alloc((size_t)N_GRAPHS * 64 * 4);
  int* bktbuf  = (int*)zb;  // alias: 6.4 MB bucket buffer consumed before zb first written

  hipMemsetAsync(hp, 0, (size_t)N_GRAPHS * 64 * 4, stream);

  edge_count<<<NBLK, 256, 0, stream>>>(dst, cnt);
  col_scan<<<NBUCKET, NBLK, 0, stream>>>(cnt, tot);
  base_scan<<<1, 256, 0, stream>>>(tot, bktbase);
  edge_place<<<NBLK, 256, 0, stream>>>(src, dst, cnt, bktbase, bktbuf);
  bucket_sort<<<NBUCKET, 256, 0, stream>>>(tot, bktbase, bktbuf, rp, ci);

  const int GB = (N_NODES + 127) / 128;    // 782 blocks (128 thr = 32 grp x 4 nodes)
  const int AB = (N_NODES + 3) / 4;        // 25000

  // conv0: proj (K=128, fp32 in) -> bf16 h; agg -> bf16 z; W0b-GEMM (pre BN-relu) -> bf16 h
  gemm_kernel<128, 0, 0, 0><<<GB, 128, 0, stream>>>(
      x, nullptr, W0a, nullptr, nullptr, nullptr, nullptr, nullptr, nullptr, hb);
  agg_kernel<<<AB, 256, 0, stream>>>(hb, rp, ci, zb);
  gemm_kernel<64, 1, 1, 1><<<GB, 128, 0, stream>>>(
      nullptr, zb, W0b, b0a, g0, be0, b0b, nullptr, nullptr, hb);

  for (int l = 0; l < 2; ++l) {
    agg_kernel<<<AB, 256, 0, stream>>>(hb, rp, ci, zb);
    gemm_kernel<64, 1, 0, 2><<<GB, 128, 0, stream>>>(
        nullptr, zb, Wsa + l * 4096, nullptr, nullptr, nullptr,
        bsa + l * 64, gs + l * 64, bes + l * 64, zb);  // in-place bf16 (wave-lockstep safe)
    gemm_kernel<64, 1, 0, 1><<<GB, 128, 0, stream>>>(
        nullptr, zb, Wsb + l * 4096, nullptr, nullptr, nullptr,
        bsb + l * 64, nullptr, nullptr, hb);
  }

  pool_kernel<<<256, 256, 0, stream>>>(hb, bat, hp);
  cls_kernel<<<N_GRAPHS, 64, 0, stream>>>(hp, Wl1, bl1, Wl2, bl2, (float*)d_out);
}

// Round 10
// 302.694 us; speedup vs baseline: 2.1313x; 1.3579x over previous
//
#include <hip/hip_runtime.h>

#define N_NODES 100000
#define N_EDGES 1600000
#define IN_DIM 128
#define DIM_H 64
#define N_GRAPHS 64

#define BKT_BITS 9
#define BKT_SIZE 512
#define NBUCKET ((N_NODES + BKT_SIZE - 1) / BKT_SIZE)  /* 196 */
#define NBLK 256
#define EPB ((N_EDGES + NBLK - 1) / NBLK)              /* 6250 */

__device__ __forceinline__ float relu(float v) { return v > 0.f ? v : 0.f; }
#define BN_SCALE 0.99999500003749968f  /* 1/sqrt(1+1e-5) */

typedef __attribute__((ext_vector_type(8))) short bf16x8;
typedef __attribute__((ext_vector_type(4))) float f32x4;

__device__ __forceinline__ float bf2f(unsigned short u) {
  return __uint_as_float(((unsigned int)u) << 16);
}
__device__ __forceinline__ unsigned short f2bf(float f) {
  unsigned int u = __float_as_uint(f);
  u += 0x7FFFu + ((u >> 16) & 1u);   // round-to-nearest-even
  return (unsigned short)(u >> 16);
}

// ---------------- CSR build: 3-phase block-private counting sort ----------------
__global__ __launch_bounds__(256) void edge_count(const int* __restrict__ dst,
                                                  int* __restrict__ cnt) {
  __shared__ int hist[NBUCKET];
  int tid = threadIdx.x, blk = blockIdx.x;
  if (tid < NBUCKET) hist[tid] = 0;
  __syncthreads();
  int beg = blk * EPB, end = beg + EPB > N_EDGES ? N_EDGES : beg + EPB;
  for (int i = beg + tid; i < end; i += 256) atomicAdd(&hist[dst[i] >> BKT_BITS], 1);
  __syncthreads();
  if (tid < NBUCKET) cnt[blk * NBUCKET + tid] = hist[tid];
}

__global__ __launch_bounds__(256) void col_scan(int* __restrict__ cnt,
                                                int* __restrict__ tot) {
  __shared__ int sd[NBLK];
  int b = blockIdx.x, tid = threadIdx.x;
  int v = cnt[tid * NBUCKET + b];
  sd[tid] = v;
  __syncthreads();
  for (int off = 1; off < NBLK; off <<= 1) {
    int t = (tid >= off) ? sd[tid - off] : 0;
    __syncthreads();
    sd[tid] += t;
    __syncthreads();
  }
  cnt[tid * NBUCKET + b] = sd[tid] - v;
  if (tid == NBLK - 1) tot[b] = sd[tid];
}

__global__ void base_scan(const int* __restrict__ tot, int* __restrict__ base) {
  __shared__ int sd[256];
  int tid = threadIdx.x;
  int v = (tid < NBUCKET) ? tot[tid] : 0;
  sd[tid] = v;
  __syncthreads();
  for (int off = 1; off < 256; off <<= 1) {
    int t = (tid >= off) ? sd[tid - off] : 0;
    __syncthreads();
    sd[tid] += t;
    __syncthreads();
  }
  if (tid < NBUCKET) base[tid] = sd[tid] - v;
}

__global__ __launch_bounds__(256) void edge_place(const int* __restrict__ src,
                                                  const int* __restrict__ dst,
                                                  const int* __restrict__ cnt,
                                                  const int* __restrict__ base,
                                                  int* __restrict__ bktbuf) {
  __shared__ int curs[NBUCKET];
  int tid = threadIdx.x, blk = blockIdx.x;
  if (tid < NBUCKET) curs[tid] = base[tid] + cnt[blk * NBUCKET + tid];
  __syncthreads();
  int beg = blk * EPB, end = beg + EPB > N_EDGES ? N_EDGES : beg + EPB;
  for (int i = beg + tid; i < end; i += 256) {
    int d = dst[i];
    int b = d >> BKT_BITS;
    int pos = atomicAdd(&curs[b], 1);
    bktbuf[pos] = src[i] | ((d & (BKT_SIZE - 1)) << 17);
  }
}

__global__ __launch_bounds__(256) void bucket_sort(const int* __restrict__ tot,
                                                   const int* __restrict__ bktbase,
                                                   const int* __restrict__ bktbuf,
                                                   int* __restrict__ rp,
                                                   int* __restrict__ ci) {
  __shared__ int hist[BKT_SIZE];
  __shared__ int partial[256];
  int b = blockIdx.x;
  int tid = threadIdx.x;
  int nb = tot[b];
  int base = bktbase[b];
  const int* buf = bktbuf + base;
  hist[tid] = 0;
  hist[tid + 256] = 0;
  __syncthreads();
  for (int i = tid; i < nb; i += 256) atomicAdd(&hist[buf[i] >> 17], 1);
  __syncthreads();
  int v0 = hist[2 * tid], v1 = hist[2 * tid + 1];
  int s = v0 + v1;
  partial[tid] = s;
  __syncthreads();
  for (int off = 1; off < 256; off <<= 1) {
    int t = (tid >= off) ? partial[tid - off] : 0;
    __syncthreads();
    partial[tid] += t;
    __syncthreads();
  }
  int excl = partial[tid] - s;
  int node0 = b * BKT_SIZE + 2 * tid;
  if (node0 < N_NODES) rp[node0] = base + excl;
  if (node0 + 1 < N_NODES) rp[node0 + 1] = base + excl + v0;
  __syncthreads();
  hist[2 * tid] = excl;
  hist[2 * tid + 1] = excl + v0;
  __syncthreads();
  for (int i = tid; i < nb; i += 256) {
    int p = buf[i];
    int pos = atomicAdd(&hist[p >> 17], 1);
    ci[base + pos] = p & 0x1FFFF;
  }
  if (b == 0 && tid == 0) rp[N_NODES] = N_EDGES;
}

// ---------------- aggregation: bf16 gathers, 16-deep MLP, fp32 accumulate ----------------
// EPI01 = 1: fused conv0 elementwise relu((v+ba)*C*g+be) at write.
template <int EPI01>
__global__ __launch_bounds__(256) void agg_kernel(const unsigned short* __restrict__ hb,
                                                  const int* __restrict__ rp,
                                                  const int* __restrict__ ci,
                                                  const float* __restrict__ ba,
                                                  const float* __restrict__ g,
                                                  const float* __restrict__ be,
                                                  unsigned short* __restrict__ zb) {
  int wid = (blockIdx.x * 256 + threadIdx.x) >> 6;
  if (wid >= N_NODES) return;
  int lane = threadIdx.x & 63;
  int eg = lane >> 4;        // edge subgroup 0..3
  int dq = lane & 15;        // 4-dim slot within row
  int beg = rp[wid], end = rp[wid + 1];
  float q0[4] = {0.f, 0.f, 0.f, 0.f};
  float q1[4] = {0.f, 0.f, 0.f, 0.f};
  float q2[4] = {0.f, 0.f, 0.f, 0.f};
  float q3[4] = {0.f, 0.f, 0.f, 0.f};
  int e = beg;
  for (; e + 16 <= end; e += 16) {
    int i0 = ci[e + eg];
    int i1 = ci[e + 4 + eg];
    int i2 = ci[e + 8 + eg];
    int i3 = ci[e + 12 + eg];
    ushort4 v0 = *(const ushort4*)(hb + (size_t)i0 * 64 + dq * 4);
    ushort4 v1 = *(const ushort4*)(hb + (size_t)i1 * 64 + dq * 4);
    ushort4 v2 = *(const ushort4*)(hb + (size_t)i2 * 64 + dq * 4);
    ushort4 v3 = *(const ushort4*)(hb + (size_t)i3 * 64 + dq * 4);
    q0[0] += bf2f(v0.x); q0[1] += bf2f(v0.y); q0[2] += bf2f(v0.z); q0[3] += bf2f(v0.w);
    q1[0] += bf2f(v1.x); q1[1] += bf2f(v1.y); q1[2] += bf2f(v1.z); q1[3] += bf2f(v1.w);
    q2[0] += bf2f(v2.x); q2[1] += bf2f(v2.y); q2[2] += bf2f(v2.z); q2[3] += bf2f(v2.w);
    q3[0] += bf2f(v3.x); q3[1] += bf2f(v3.y); q3[2] += bf2f(v3.z); q3[3] += bf2f(v3.w);
  }
  for (; e + 8 <= end; e += 8) {
    int i0 = ci[e + eg];
    int i1 = ci[e + 4 + eg];
    ushort4 v0 = *(const ushort4*)(hb + (size_t)i0 * 64 + dq * 4);
    ushort4 v1 = *(const ushort4*)(hb + (size_t)i1 * 64 + dq * 4);
    q0[0] += bf2f(v0.x); q0[1] += bf2f(v0.y); q0[2] += bf2f(v0.z); q0[3] += bf2f(v0.w);
    q1[0] += bf2f(v1.x); q1[1] += bf2f(v1.y); q1[2] += bf2f(v1.z); q1[3] += bf2f(v1.w);
  }
  for (; e < end; e += 4) {
    if (e + eg < end) {
      ushort4 v0 = *(const ushort4*)(hb + (size_t)ci[e + eg] * 64 + dq * 4);
      q0[0] += bf2f(v0.x); q0[1] += bf2f(v0.y); q0[2] += bf2f(v0.z); q0[3] += bf2f(v0.w);
    }
  }
  float a0 = (q0[0] + q1[0]) + (q2[0] + q3[0]);
  float a1 = (q0[1] + q1[1]) + (q2[1] + q3[1]);
  float a2 = (q0[2] + q1[2]) + (q2[2] + q3[2]);
  float a3 = (q0[3] + q1[3]) + (q2[3] + q3[3]);
  a0 += __shfl_xor(a0, 16, 64); a1 += __shfl_xor(a1, 16, 64);
  a2 += __shfl_xor(a2, 16, 64); a3 += __shfl_xor(a3, 16, 64);
  a0 += __shfl_xor(a0, 32, 64); a1 += __shfl_xor(a1, 32, 64);
  a2 += __shfl_xor(a2, 32, 64); a3 += __shfl_xor(a3, 32, 64);
  if (eg == 0) {
    ushort4 s = *(const ushort4*)(hb + (size_t)wid * 64 + dq * 4);
    float r0 = a0 + bf2f(s.x), r1 = a1 + bf2f(s.y);
    float r2 = a2 + bf2f(s.z), r3 = a3 + bf2f(s.w);
    if (EPI01) {
      float4 bav = *(const float4*)(ba + dq * 4);
      float4 gv = *(const float4*)(g + dq * 4);
      float4 bev = *(const float4*)(be + dq * 4);
      r0 = relu(fmaf((r0 + bav.x) * BN_SCALE, gv.x, bev.x));
      r1 = relu(fmaf((r1 + bav.y) * BN_SCALE, gv.y, bev.y));
      r2 = relu(fmaf((r2 + bav.z) * BN_SCALE, gv.z, bev.z));
      r3 = relu(fmaf((r3 + bav.w) * BN_SCALE, gv.w, bev.w));
    }
    ushort4 o;
    o.x = f2bf(r0); o.y = f2bf(r1); o.z = f2bf(r2); o.w = f2bf(r3);
    *(ushort4*)(zb + (size_t)wid * 64 + dq * 4) = o;
  }
}

// ---------------- MFMA GEMM: [N_NODES x K] @ W[K x 64] -> bf16 [N_NODES x 64] ----------------
// 256 thr = 4 waves x 16 nodes. A from global (fp32 if AFP32 else bf16 rows).
// W staged to LDS as bf16 W^T, XOR-swizzled (o&7)<<4 to break stride-K bank conflicts.
// EPI: 0 none, 1 relu(acc+bias), 2 relu((acc+bias)*C*g+be). KC = K/32.
template <int KC, int AFP32, int EPI>
__global__ __launch_bounds__(256) void mfma_gemm(const float* __restrict__ af,
                                                 const unsigned short* __restrict__ ab,
                                                 const float* __restrict__ W,
                                                 const float* __restrict__ bias,
                                                 const float* __restrict__ g,
                                                 const float* __restrict__ be,
                                                 unsigned short* __restrict__ outb) {
  constexpr int K = KC * 32;
  __shared__ unsigned short lw[K * 64];
  int tid = threadIdx.x;
#pragma unroll
  for (int i = 0; i < K * 64 / 256; ++i) {
    int idx = tid + i * 256;                 // idx = k*64 + o (coalesced global read)
    int k = idx >> 6, o = idx & 63;
    unsigned int boff = (unsigned int)((o * K + k) * 2) ^ ((unsigned int)(o & 7) << 4);
    *(unsigned short*)((char*)lw + boff) = f2bf(W[idx]);
  }
  __syncthreads();
  int lane = tid & 63;
  int wave = tid >> 6;
  int arow = lane & 15;                      // A fragment row
  int kq = lane >> 4;                        // k-quarter 0..3
  int mb = blockIdx.x * 64 + wave * 16;
  int anode = mb + arow;
  if (anode >= N_NODES) anode = N_NODES - 1;
  f32x4 acc[4];
#pragma unroll
  for (int t = 0; t < 4; ++t) acc[t] = (f32x4){0.f, 0.f, 0.f, 0.f};
#pragma unroll
  for (int kc = 0; kc < KC; ++kc) {
    bf16x8 afrag;
    if (AFP32) {
      const float* ap = af + (size_t)anode * K + kc * 32 + kq * 8;
      float4 u0 = *(const float4*)(ap);
      float4 u1 = *(const float4*)(ap + 4);
      afrag[0] = (short)f2bf(u0.x); afrag[1] = (short)f2bf(u0.y);
      afrag[2] = (short)f2bf(u0.z); afrag[3] = (short)f2bf(u0.w);
      afrag[4] = (short)f2bf(u1.x); afrag[5] = (short)f2bf(u1.y);
      afrag[6] = (short)f2bf(u1.z); afrag[7] = (short)f2bf(u1.w);
    } else {
      afrag = *(const bf16x8*)(ab + (size_t)anode * K + kc * 32 + kq * 8);
    }
#pragma unroll
    for (int t = 0; t < 4; ++t) {
      int o = t * 16 + (lane & 15);          // B fragment col
      unsigned int boff = (unsigned int)((o * K + kc * 32 + kq * 8) * 2) ^
                          ((unsigned int)(o & 7) << 4);
      bf16x8 bfrag = *(const bf16x8*)((char*)lw + boff);
      acc[t] = __builtin_amdgcn_mfma_f32_16x16x32_bf16(afrag, bfrag, acc[t], 0, 0, 0);
    }
  }
  // C layout: col = t*16 + (lane&15), row = kq*4 + r  (m89-verified)
  int ccol = lane & 15;
#pragma unroll
  for (int t = 0; t < 4; ++t) {
    int c = t * 16 + ccol;
    float bv = (EPI != 0) ? bias[c] : 0.f;
    float gv = (EPI == 2) ? g[c] : 0.f;
    float bev = (EPI == 2) ? be[c] : 0.f;
#pragma unroll
    for (int r = 0; r < 4; ++r) {
      int node = mb + kq * 4 + r;
      if (node < N_NODES) {
        float v = acc[t][r];
        if (EPI == 1) v = relu(v + bv);
        else if (EPI == 2) v = relu(fmaf((v + bv) * BN_SCALE, gv, bev));
        outb[(size_t)node * 64 + c] = f2bf(v);
      }
    }
  }
}

// ---------------- pool: bf16 h rows, fp32 accumulate ----------------
__global__ __launch_bounds__(256) void pool_kernel(const unsigned short* __restrict__ hb,
                                                   const int* __restrict__ batch,
                                                   float* __restrict__ hp) {
  const int CH = (N_NODES + 1023) / 1024;
  int w = (blockIdx.x * blockDim.x + threadIdx.x) >> 6;
  int lane = threadIdx.x & 63;
  int start = w * CH;
  if (start >= N_NODES) return;
  int end = start + CH;
  if (end > N_NODES) end = N_NODES;
  int cur = batch[start];
  float acc = 0.f;
  for (int n = start; n < end; ++n) {
    int b = batch[n];
    if (b != cur) {
      atomicAdd(&hp[cur * 64 + lane], acc);
      acc = 0.f;
      cur = b;
    }
    acc += bf2f(hb[(size_t)n * 64 + lane]);
  }
  atomicAdd(&hp[cur * 64 + lane], acc);
}

// ---------------- classifier ----------------
__global__ __launch_bounds__(64) void cls_kernel(const float* __restrict__ hp,
                                                 const float* __restrict__ Wl1,
                                                 const float* __restrict__ bl1,
                                                 const float* __restrict__ Wl2,
                                                 const float* __restrict__ bl2,
                                                 float* __restrict__ out) {
  int g = blockIdx.x;
  int d = threadIdx.x;
  const float* hrow = hp + g * 64;
  float acc = bl1[d];
#pragma unroll 8
  for (int k = 0; k < 64; ++k) {
    float v = hrow[k];
    float w = Wl1[k * 64 + d] + Wl1[(64 + k) * 64 + d] + Wl1[(128 + k) * 64 + d];
    acc = fmaf(v, w, acc);
  }
  float t = relu(acc);
  float p0 = t * Wl2[d * 2 + 0];
  float p1 = t * Wl2[d * 2 + 1];
#pragma unroll
  for (int off = 32; off > 0; off >>= 1) {
    p0 += __shfl_xor(p0, off, 64);
    p1 += __shfl_xor(p1, off, 64);
  }
  if (d == 0) {
    float z0 = p0 + bl2[0];
    float z1 = p1 + bl2[1];
    float m = fmaxf(z0, z1);
    float lse = m + logf(expf(z0 - m) + expf(z1 - m));
    out[g * 2 + 0] = z0 - lse;
    out[g * 2 + 1] = z1 - lse;
  }
}

extern "C" void kernel_launch(void* const* d_in, const int* in_sizes, int n_in,
                              void* d_out, int out_size, void* d_ws, size_t ws_size,
                              hipStream_t stream) {
  const float* x   = (const float*)d_in[0];
  const int*   ei  = (const int*)d_in[1];
  const int*   bat = (const int*)d_in[2];
  const float* W0a = (const float*)d_in[3];
  const float* b0a = (const float*)d_in[4];
  const float* g0  = (const float*)d_in[5];
  const float* be0 = (const float*)d_in[6];
  const float* W0b = (const float*)d_in[7];
  const float* b0b = (const float*)d_in[8];
  const float* Wsa = (const float*)d_in[9];
  const float* bsa = (const float*)d_in[10];
  const float* gs  = (const float*)d_in[11];
  const float* bes = (const float*)d_in[12];
  const float* Wsb = (const float*)d_in[13];
  const float* bsb = (const float*)d_in[14];
  const float* Wl1 = (const float*)d_in[15];
  const float* bl1 = (const float*)d_in[16];
  const float* Wl2 = (const float*)d_in[17];
  const float* bl2 = (const float*)d_in[18];
  const int* src = ei;
  const int* dst = ei + N_EDGES;

  char* ws = (char*)d_ws;
  size_t off = 0;
  auto alloc = [&](size_t bytes) { void* p = ws + off; off += (bytes + 255) & ~255ull; return p; };
  int* rp      = (int*)alloc((size_t)(N_NODES + 1) * 4);
  int* cnt     = (int*)alloc((size_t)NBLK * NBUCKET * 4);
  int* tot     = (int*)alloc((size_t)NBUCKET * 4);
  int* bktbase = (int*)alloc((size_t)NBUCKET * 4);
  int* ci      = (int*)alloc((size_t)N_EDGES * 4);
  unsigned short* zb = (unsigned short*)alloc((size_t)N_NODES * 64 * 2);
  unsigned short* hb = (unsigned short*)alloc((size_t)N_NODES * 64 * 2);
  unsigned short* tb = (unsigned short*)alloc((size_t)N_NODES * 64 * 2);
  float* hp    = (float*)alloc((size_t)N_GRAPHS * 64 * 4);
  int* bktbuf  = (int*)zb;  // alias: 6.4 MB bucket buffer consumed before zb first written

  hipMemsetAsync(hp, 0, (size_t)N_GRAPHS * 64 * 4, stream);

  edge_count<<<NBLK, 256, 0, stream>>>(dst, cnt);
  col_scan<<<NBUCKET, NBLK, 0, stream>>>(cnt, tot);
  base_scan<<<1, 256, 0, stream>>>(tot, bktbase);
  edge_place<<<NBLK, 256, 0, stream>>>(src, dst, cnt, bktbase, bktbuf);
  bucket_sort<<<NBUCKET, 256, 0, stream>>>(tot, bktbase, bktbuf, rp, ci);

  const int GB = (N_NODES + 63) / 64;      // 1563 blocks (4 waves x 16 nodes)
  const int AB = (N_NODES + 3) / 4;        // 25000

  // conv0: proj x@W0a (fp32 A, K=128) -> hb; agg+fused BN-relu -> zb(t); t@W0b+b0b relu -> hb
  mfma_gemm<4, 1, 0><<<GB, 256, 0, stream>>>(
      x, nullptr, W0a, nullptr, nullptr, nullptr, hb);
  agg_kernel<1><<<AB, 256, 0, stream>>>(hb, rp, ci, b0a, g0, be0, zb);
  mfma_gemm<2, 0, 1><<<GB, 256, 0, stream>>>(
      nullptr, zb, W0b, b0b, nullptr, nullptr, hb);

  for (int l = 0; l < 2; ++l) {
    agg_kernel<0><<<AB, 256, 0, stream>>>(hb, rp, ci, nullptr, nullptr, nullptr, zb);
    mfma_gemm<2, 0, 2><<<GB, 256, 0, stream>>>(
        nullptr, zb, Wsa + l * 4096, bsa + l * 64, gs + l * 64, bes + l * 64, tb);
    mfma_gemm<2, 0, 1><<<GB, 256, 0, stream>>>(
        nullptr, tb, Wsb + l * 4096, bsb + l * 64, nullptr, nullptr, hb);
  }

  pool_kernel<<<256, 256, 0, stream>>>(hb, bat, hp);
  cls_kernel<<<N_GRAPHS, 64, 0, stream>>>(hp, Wl1, bl1, Wl2, bl2, (float*)d_out);
}

// Round 11
// 266.265 us; speedup vs baseline: 2.4229x; 1.1368x over previous
//
#include <hip/hip_runtime.h>

#define N_NODES 100000
#define N_EDGES 1600000
#define IN_DIM 128
#define DIM_H 64
#define N_GRAPHS 64

#define BKT_BITS 9
#define BKT_SIZE 512
#define NBUCKET ((N_NODES + BKT_SIZE - 1) / BKT_SIZE)  /* 196 */
#define NBLK 256
#define EPB ((N_EDGES + NBLK - 1) / NBLK)              /* 6250 */

__device__ __forceinline__ float relu(float v) { return v > 0.f ? v : 0.f; }
#define BN_SCALE 0.99999500003749968f  /* 1/sqrt(1+1e-5) */

typedef __attribute__((ext_vector_type(8))) short bf16x8;
typedef __attribute__((ext_vector_type(4))) float f32x4;

__device__ __forceinline__ float bf2f(unsigned short u) {
  return __uint_as_float(((unsigned int)u) << 16);
}
__device__ __forceinline__ float bflo(unsigned int u) {
  return __uint_as_float(u << 16);
}
__device__ __forceinline__ float bfhi(unsigned int u) {
  return __uint_as_float(u & 0xFFFF0000u);
}
__device__ __forceinline__ unsigned short f2bf(float f) {
  unsigned int u = __float_as_uint(f);
  u += 0x7FFFu + ((u >> 16) & 1u);   // round-to-nearest-even
  return (unsigned short)(u >> 16);
}
__device__ __forceinline__ void acc8(float* a, uint4 u) {
  a[0] += bflo(u.x); a[1] += bfhi(u.x);
  a[2] += bflo(u.y); a[3] += bfhi(u.y);
  a[4] += bflo(u.z); a[5] += bfhi(u.z);
  a[6] += bflo(u.w); a[7] += bfhi(u.w);
}

// ---------------- CSR build: 3-phase counting sort, per-WAVE histograms ----------------
__global__ __launch_bounds__(256) void edge_count(const int* __restrict__ dst,
                                                  int* __restrict__ cnt) {
  __shared__ int hist[4 * NBUCKET];
  int tid = threadIdx.x, blk = blockIdx.x;
  for (int i = tid; i < 4 * NBUCKET; i += 256) hist[i] = 0;
  __syncthreads();
  int* h = hist + (tid >> 6) * NBUCKET;
  int beg = blk * EPB, end = beg + EPB > N_EDGES ? N_EDGES : beg + EPB;
  for (int i = beg + tid; i < end; i += 256) atomicAdd(&h[dst[i] >> BKT_BITS], 1);
  __syncthreads();
  for (int i = tid; i < 4 * NBUCKET; i += 256) cnt[blk * 4 * NBUCKET + i] = hist[i];
}

// exclusive scan over 1024 units per bucket
__global__ __launch_bounds__(256) void col_scan(int* __restrict__ cnt,
                                                int* __restrict__ tot) {
  __shared__ int sd[256];
  int b = blockIdx.x, tid = threadIdx.x;
  int v0 = cnt[(4 * tid + 0) * NBUCKET + b];
  int v1 = cnt[(4 * tid + 1) * NBUCKET + b];
  int v2 = cnt[(4 * tid + 2) * NBUCKET + b];
  int v3 = cnt[(4 * tid + 3) * NBUCKET + b];
  int s = v0 + v1 + v2 + v3;
  sd[tid] = s;
  __syncthreads();
  for (int off = 1; off < 256; off <<= 1) {
    int t = (tid >= off) ? sd[tid - off] : 0;
    __syncthreads();
    sd[tid] += t;
    __syncthreads();
  }
  int excl = sd[tid] - s;
  cnt[(4 * tid + 0) * NBUCKET + b] = excl;
  cnt[(4 * tid + 1) * NBUCKET + b] = excl + v0;
  cnt[(4 * tid + 2) * NBUCKET + b] = excl + v0 + v1;
  cnt[(4 * tid + 3) * NBUCKET + b] = excl + v0 + v1 + v2;
  if (tid == 255) tot[b] = sd[255];
}

__global__ void base_scan(const int* __restrict__ tot, int* __restrict__ base) {
  __shared__ int sd[256];
  int tid = threadIdx.x;
  int v = (tid < NBUCKET) ? tot[tid] : 0;
  sd[tid] = v;
  __syncthreads();
  for (int off = 1; off < 256; off <<= 1) {
    int t = (tid >= off) ? sd[tid - off] : 0;
    __syncthreads();
    sd[tid] += t;
    __syncthreads();
  }
  if (tid < NBUCKET) base[tid] = sd[tid] - v;
}

__global__ __launch_bounds__(256) void edge_place(const int* __restrict__ src,
                                                  const int* __restrict__ dst,
                                                  const int* __restrict__ cnt,
                                                  const int* __restrict__ base,
                                                  int* __restrict__ bktbuf) {
  __shared__ int curs[4 * NBUCKET];
  int tid = threadIdx.x, blk = blockIdx.x;
  for (int i = tid; i < 4 * NBUCKET; i += 256)
    curs[i] = base[i % NBUCKET] + cnt[blk * 4 * NBUCKET + i];
  __syncthreads();
  int* cw = curs + (tid >> 6) * NBUCKET;
  int beg = blk * EPB, end = beg + EPB > N_EDGES ? N_EDGES : beg + EPB;
  for (int i = beg + tid; i < end; i += 256) {
    int d = dst[i];
    int b = d >> BKT_BITS;
    int pos = atomicAdd(&cw[b], 1);
    bktbuf[pos] = src[i] | ((d & (BKT_SIZE - 1)) << 17);
  }
}

__global__ __launch_bounds__(256) void bucket_sort(const int* __restrict__ tot,
                                                   const int* __restrict__ bktbase,
                                                   const int* __restrict__ bktbuf,
                                                   int* __restrict__ rp,
                                                   int* __restrict__ ci) {
  __shared__ int hist[BKT_SIZE];
  __shared__ int partial[256];
  int b = blockIdx.x;
  int tid = threadIdx.x;
  int nb = tot[b];
  int base = bktbase[b];
  const int* buf = bktbuf + base;
  hist[tid] = 0;
  hist[tid + 256] = 0;
  __syncthreads();
  for (int i = tid; i < nb; i += 256) atomicAdd(&hist[buf[i] >> 17], 1);
  __syncthreads();
  int v0 = hist[2 * tid], v1 = hist[2 * tid + 1];
  int s = v0 + v1;
  partial[tid] = s;
  __syncthreads();
  for (int off = 1; off < 256; off <<= 1) {
    int t = (tid >= off) ? partial[tid - off] : 0;
    __syncthreads();
    partial[tid] += t;
    __syncthreads();
  }
  int excl = partial[tid] - s;
  int node0 = b * BKT_SIZE + 2 * tid;
  if (node0 < N_NODES) rp[node0] = base + excl;
  if (node0 + 1 < N_NODES) rp[node0 + 1] = base + excl + v0;
  __syncthreads();
  hist[2 * tid] = excl;
  hist[2 * tid + 1] = excl + v0;
  __syncthreads();
  for (int i = tid; i < nb; i += 256) {
    int p = buf[i];
    int pos = atomicAdd(&hist[p >> 17], 1);
    ci[base + pos] = p & 0x1FFFF;
  }
  if (b == 0 && tid == 0) rp[N_NODES] = N_EDGES;
}

// ---------------- aggregation: 8-edge-parallel, 16 B/lane bf16 gathers ----------------
// EPI01 = 1: fused conv0 elementwise relu((v+ba)*C*g+be) at write.
template <int EPI01>
__global__ __launch_bounds__(256) void agg_kernel(const unsigned short* __restrict__ hb,
                                                  const int* __restrict__ rp,
                                                  const int* __restrict__ ci,
                                                  const float* __restrict__ ba,
                                                  const float* __restrict__ g,
                                                  const float* __restrict__ be,
                                                  unsigned short* __restrict__ zb) {
  int wid = (blockIdx.x * 256 + threadIdx.x) >> 6;
  if (wid >= N_NODES) return;
  int lane = threadIdx.x & 63;
  int eg = lane >> 3;        // edge subgroup 0..7
  int dq = lane & 7;         // 8-dim slot within row
  int beg = rp[wid], end = rp[wid + 1];
  float a[8] = {0.f, 0.f, 0.f, 0.f, 0.f, 0.f, 0.f, 0.f};
  float b[8] = {0.f, 0.f, 0.f, 0.f, 0.f, 0.f, 0.f, 0.f};
  int e = beg;
  for (; e + 16 <= end; e += 16) {
    int i0 = ci[e + eg];
    int i1 = ci[e + 8 + eg];
    uint4 u0 = *(const uint4*)(hb + (size_t)i0 * 64 + dq * 8);
    uint4 u1 = *(const uint4*)(hb + (size_t)i1 * 64 + dq * 8);
    acc8(a, u0);
    acc8(b, u1);
  }
  for (; e + 8 <= end; e += 8) {
    int i0 = ci[e + eg];
    uint4 u0 = *(const uint4*)(hb + (size_t)i0 * 64 + dq * 8);
    acc8(a, u0);
  }
  if (e + eg < end) {
    uint4 u0 = *(const uint4*)(hb + (size_t)ci[e + eg] * 64 + dq * 8);
    acc8(a, u0);
  }
#pragma unroll
  for (int j = 0; j < 8; ++j) {
    a[j] += b[j];
    a[j] += __shfl_xor(a[j], 8, 64);
    a[j] += __shfl_xor(a[j], 16, 64);
    a[j] += __shfl_xor(a[j], 32, 64);
  }
  if (eg == 0) {
    uint4 s = *(const uint4*)(hb + (size_t)wid * 64 + dq * 8);
    float r[8];
    r[0] = a[0] + bflo(s.x); r[1] = a[1] + bfhi(s.x);
    r[2] = a[2] + bflo(s.y); r[3] = a[3] + bfhi(s.y);
    r[4] = a[4] + bflo(s.z); r[5] = a[5] + bfhi(s.z);
    r[6] = a[6] + bflo(s.w); r[7] = a[7] + bfhi(s.w);
    if (EPI01) {
      float4 ba0 = *(const float4*)(ba + dq * 8);
      float4 ba1 = *(const float4*)(ba + dq * 8 + 4);
      float4 g0v = *(const float4*)(g + dq * 8);
      float4 g1v = *(const float4*)(g + dq * 8 + 4);
      float4 be0v = *(const float4*)(be + dq * 8);
      float4 be1v = *(const float4*)(be + dq * 8 + 4);
      r[0] = relu(fmaf((r[0] + ba0.x) * BN_SCALE, g0v.x, be0v.x));
      r[1] = relu(fmaf((r[1] + ba0.y) * BN_SCALE, g0v.y, be0v.y));
      r[2] = relu(fmaf((r[2] + ba0.z) * BN_SCALE, g0v.z, be0v.z));
      r[3] = relu(fmaf((r[3] + ba0.w) * BN_SCALE, g0v.w, be0v.w));
      r[4] = relu(fmaf((r[4] + ba1.x) * BN_SCALE, g1v.x, be1v.x));
      r[5] = relu(fmaf((r[5] + ba1.y) * BN_SCALE, g1v.y, be1v.y));
      r[6] = relu(fmaf((r[6] + ba1.z) * BN_SCALE, g1v.z, be1v.z));
      r[7] = relu(fmaf((r[7] + ba1.w) * BN_SCALE, g1v.w, be1v.w));
    }
    uint4 o;
    o.x = (unsigned int)f2bf(r[0]) | ((unsigned int)f2bf(r[1]) << 16);
    o.y = (unsigned int)f2bf(r[2]) | ((unsigned int)f2bf(r[3]) << 16);
    o.z = (unsigned int)f2bf(r[4]) | ((unsigned int)f2bf(r[5]) << 16);
    o.w = (unsigned int)f2bf(r[6]) | ((unsigned int)f2bf(r[7]) << 16);
    *(uint4*)(zb + (size_t)wid * 64 + dq * 8) = o;
  }
}

// ---------------- MFMA GEMM: [N_NODES x K] @ W[K x 64] -> bf16 [N_NODES x 64] ----------------
// 256 thr = 4 waves x 16 nodes. W staged to LDS as bf16 W^T, XOR-swizzled (o&7)<<4.
// EPI: 0 none, 1 relu(acc+bias), 2 relu((acc+bias)*C*g+be),
//      3 relu(acc+bias) -> pool into hp by batch (no h write). KC = K/32.
template <int KC, int AFP32, int EPI>
__global__ __launch_bounds__(256) void mfma_gemm(const float* __restrict__ af,
                                                 const unsigned short* __restrict__ ab,
                                                 const float* __restrict__ W,
                                                 const float* __restrict__ bias,
                                                 const float* __restrict__ g,
                                                 const float* __restrict__ be,
                                                 unsigned short* __restrict__ outb,
                                                 const int* __restrict__ batch,
                                                 float* __restrict__ hp) {
  constexpr int K = KC * 32;
  __shared__ unsigned short lw[K * 64];
  int tid = threadIdx.x;
#pragma unroll
  for (int i = 0; i < K * 64 / 256; ++i) {
    int idx = tid + i * 256;                 // idx = k*64 + o (coalesced global read)
    int k = idx >> 6, o = idx & 63;
    unsigned int boff = (unsigned int)((o * K + k) * 2) ^ ((unsigned int)(o & 7) << 4);
    *(unsigned short*)((char*)lw + boff) = f2bf(W[idx]);
  }
  __syncthreads();
  int lane = tid & 63;
  int wave = tid >> 6;
  int arow = lane & 15;                      // A fragment row
  int kq = lane >> 4;                        // k-quarter 0..3
  int mb = blockIdx.x * 64 + wave * 16;
  if (mb >= N_NODES) return;                 // whole wave out of range (no barriers below)
  int anode = mb + arow;
  if (anode >= N_NODES) anode = N_NODES - 1;
  f32x4 acc[4];
#pragma unroll
  for (int t = 0; t < 4; ++t) acc[t] = (f32x4){0.f, 0.f, 0.f, 0.f};
#pragma unroll
  for (int kc = 0; kc < KC; ++kc) {
    bf16x8 afrag;
    if (AFP32) {
      const float* ap = af + (size_t)anode * K + kc * 32 + kq * 8;
      float4 u0 = *(const float4*)(ap);
      float4 u1 = *(const float4*)(ap + 4);
      afrag[0] = (short)f2bf(u0.x); afrag[1] = (short)f2bf(u0.y);
      afrag[2] = (short)f2bf(u0.z); afrag[3] = (short)f2bf(u0.w);
      afrag[4] = (short)f2bf(u1.x); afrag[5] = (short)f2bf(u1.y);
      afrag[6] = (short)f2bf(u1.z); afrag[7] = (short)f2bf(u1.w);
    } else {
      afrag = *(const bf16x8*)(ab + (size_t)anode * K + kc * 32 + kq * 8);
    }
#pragma unroll
    for (int t = 0; t < 4; ++t) {
      int o = t * 16 + (lane & 15);          // B fragment col
      unsigned int boff = (unsigned int)((o * K + kc * 32 + kq * 8) * 2) ^
                          ((unsigned int)(o & 7) << 4);
      bf16x8 bfrag = *(const bf16x8*)((char*)lw + boff);
      acc[t] = __builtin_amdgcn_mfma_f32_16x16x32_bf16(afrag, bfrag, acc[t], 0, 0, 0);
    }
  }
  // C layout: col = t*16 + (lane&15), row = kq*4 + r  (m89-verified)
  int ccol = lane & 15;
  if (EPI == 3) {
    int nlast = mb + 15 < N_NODES ? mb + 15 : N_NODES - 1;
    int b0 = batch[mb], b1 = batch[nlast];
    float v[4][4];
#pragma unroll
    for (int t = 0; t < 4; ++t) {
      float bv = bias[t * 16 + ccol];
#pragma unroll
      for (int r = 0; r < 4; ++r) {
        int node = mb + kq * 4 + r;
        v[t][r] = (node < N_NODES) ? relu(acc[t][r] + bv) : 0.f;
      }
    }
    if (b0 == b1) {
#pragma unroll
      for (int t = 0; t < 4; ++t) {
        float s = (v[t][0] + v[t][1]) + (v[t][2] + v[t][3]);
        s += __shfl_xor(s, 16, 64);
        s += __shfl_xor(s, 32, 64);
        if (kq == 0) atomicAdd(&hp[b0 * 64 + t * 16 + ccol], s);
      }
    } else {
      int bn[4];
#pragma unroll
      for (int r = 0; r < 4; ++r) {
        int node = mb + kq * 4 + r;
        bn[r] = batch[node < N_NODES ? node : N_NODES - 1];
      }
#pragma unroll
      for (int t = 0; t < 4; ++t)
#pragma unroll
        for (int r = 0; r < 4; ++r) {
          int node = mb + kq * 4 + r;
          if (node < N_NODES) atomicAdd(&hp[bn[r] * 64 + t * 16 + ccol], v[t][r]);
        }
    }
  } else {
#pragma unroll
    for (int t = 0; t < 4; ++t) {
      int c = t * 16 + ccol;
      float bv = (EPI != 0) ? bias[c] : 0.f;
      float gv = (EPI == 2) ? g[c] : 0.f;
      float bev = (EPI == 2) ? be[c] : 0.f;
#pragma unroll
      for (int r = 0; r < 4; ++r) {
        int node = mb + kq * 4 + r;
        if (node < N_NODES) {
          float vv = acc[t][r];
          if (EPI == 1) vv = relu(vv + bv);
          else if (EPI == 2) vv = relu(fmaf((vv + bv) * BN_SCALE, gv, bev));
          outb[(size_t)node * 64 + c] = f2bf(vv);
        }
      }
    }
  }
}

// ---------------- classifier ----------------
__global__ __launch_bounds__(64) void cls_kernel(const float* __restrict__ hp,
                                                 const float* __restrict__ Wl1,
                                                 const float* __restrict__ bl1,
                                                 const float* __restrict__ Wl2,
                                                 const float* __restrict__ bl2,
                                                 float* __restrict__ out) {
  int g = blockIdx.x;
  int d = threadIdx.x;
  const float* hrow = hp + g * 64;
  float acc = bl1[d];
#pragma unroll 8
  for (int k = 0; k < 64; ++k) {
    float v = hrow[k];
    float w = Wl1[k * 64 + d] + Wl1[(64 + k) * 64 + d] + Wl1[(128 + k) * 64 + d];
    acc = fmaf(v, w, acc);
  }
  float t = relu(acc);
  float p0 = t * Wl2[d * 2 + 0];
  float p1 = t * Wl2[d * 2 + 1];
#pragma unroll
  for (int off = 32; off > 0; off >>= 1) {
    p0 += __shfl_xor(p0, off, 64);
    p1 += __shfl_xor(p1, off, 64);
  }
  if (d == 0) {
    float z0 = p0 + bl2[0];
    float z1 = p1 + bl2[1];
    float m = fmaxf(z0, z1);
    float lse = m + logf(expf(z0 - m) + expf(z1 - m));
    out[g * 2 + 0] = z0 - lse;
    out[g * 2 + 1] = z1 - lse;
  }
}

extern "C" void kernel_launch(void* const* d_in, const int* in_sizes, int n_in,
                              void* d_out, int out_size, void* d_ws, size_t ws_size,
                              hipStream_t stream) {
  const float* x   = (const float*)d_in[0];
  const int*   ei  = (const int*)d_in[1];
  const int*   bat = (const int*)d_in[2];
  const float* W0a = (const float*)d_in[3];
  const float* b0a = (const float*)d_in[4];
  const float* g0  = (const float*)d_in[5];
  const float* be0 = (const float*)d_in[6];
  const float* W0b = (const float*)d_in[7];
  const float* b0b = (const float*)d_in[8];
  const float* Wsa = (const float*)d_in[9];
  const float* bsa = (const float*)d_in[10];
  const float* gs  = (const float*)d_in[11];
  const float* bes = (const float*)d_in[12];
  const float* Wsb = (const float*)d_in[13];
  const float* bsb = (const float*)d_in[14];
  const float* Wl1 = (const float*)d_in[15];
  const float* bl1 = (const float*)d_in[16];
  const float* Wl2 = (const float*)d_in[17];
  const float* bl2 = (const float*)d_in[18];
  const int* src = ei;
  const int* dst = ei + N_EDGES;

  char* ws = (char*)d_ws;
  size_t off = 0;
  auto alloc = [&](size_t bytes) { void* p = ws + off; off += (bytes + 255) & ~255ull; return p; };
  int* rp      = (int*)alloc((size_t)(N_NODES + 1) * 4);
  int* cnt     = (int*)alloc((size_t)NBLK * 4 * NBUCKET * 4);
  int* tot     = (int*)alloc((size_t)NBUCKET * 4);
  int* bktbase = (int*)alloc((size_t)NBUCKET * 4);
  int* ci      = (int*)alloc((size_t)N_EDGES * 4);
  unsigned short* zb = (unsigned short*)alloc((size_t)N_NODES * 64 * 2);
  unsigned short* hb = (unsigned short*)alloc((size_t)N_NODES * 64 * 2);
  unsigned short* tb = (unsigned short*)alloc((size_t)N_NODES * 64 * 2);
  float* hp    = (float*)alloc((size_t)N_GRAPHS * 64 * 4);
  int* bktbuf  = (int*)zb;  // alias: 6.4 MB bucket buffer consumed before zb first written

  hipMemsetAsync(hp, 0, (size_t)N_GRAPHS * 64 * 4, stream);

  edge_count<<<NBLK, 256, 0, stream>>>(dst, cnt);
  col_scan<<<NBUCKET, 256, 0, stream>>>(cnt, tot);
  base_scan<<<1, 256, 0, stream>>>(tot, bktbase);
  edge_place<<<NBLK, 256, 0, stream>>>(src, dst, cnt, bktbase, bktbuf);
  bucket_sort<<<NBUCKET, 256, 0, stream>>>(tot, bktbase, bktbuf, rp, ci);

  const int GB = (N_NODES + 63) / 64;      // 1563 blocks (4 waves x 16 nodes)
  const int AB = (N_NODES + 3) / 4;        // 25000

  // conv0: proj x@W0a (fp32 A, K=128) -> hb; agg+fused BN-relu -> zb; zb@W0b+b0b relu -> hb
  mfma_gemm<4, 1, 0><<<GB, 256, 0, stream>>>(
      x, nullptr, W0a, nullptr, nullptr, nullptr, hb, nullptr, nullptr);
  agg_kernel<1><<<AB, 256, 0, stream>>>(hb, rp, ci, b0a, g0, be0, zb);
  mfma_gemm<2, 0, 1><<<GB, 256, 0, stream>>>(
      nullptr, zb, W0b, b0b, nullptr, nullptr, hb, nullptr, nullptr);

  // layer 1
  agg_kernel<0><<<AB, 256, 0, stream>>>(hb, rp, ci, nullptr, nullptr, nullptr, zb);
  mfma_gemm<2, 0, 2><<<GB, 256, 0, stream>>>(
      nullptr, zb, Wsa, bsa, gs, bes, tb, nullptr, nullptr);
  mfma_gemm<2, 0, 1><<<GB, 256, 0, stream>>>(
      nullptr, tb, Wsb, bsb, nullptr, nullptr, hb, nullptr, nullptr);

  // layer 2 (final GEMM fuses pooling; no h write)
  agg_kernel<0><<<AB, 256, 0, stream>>>(hb, rp, ci, nullptr, nullptr, nullptr, zb);
  mfma_gemm<2, 0, 2><<<GB, 256, 0, stream>>>(
      nullptr, zb, Wsa + 4096, bsa + 64, gs + 64, bes + 64, tb, nullptr, nullptr);
  mfma_gemm<2, 0, 3><<<GB, 256, 0, stream>>>(
      nullptr, tb, Wsb + 4096, bsb + 64, nullptr, nullptr, nullptr, bat, hp);

  cls_kernel<<<N_GRAPHS, 64, 0, stream>>>(hp, Wl1, bl1, Wl2, bl2, (float*)d_out);
}